// Round 11
// baseline (861.519 us; speedup 1.0000x reference)
//
#include <hip/hip_runtime.h>
#include <hip/hip_bf16.h>
#include <hip/hip_fp16.h>

using bf16 = __hip_bfloat16;
using frag_ab = __attribute__((ext_vector_type(8))) short;
using f16x8  = __attribute__((ext_vector_type(8))) _Float16;
using hf16x2 = __attribute__((ext_vector_type(2))) __fp16;   // cvt_pkrtz return type
using frag_cd = __attribute__((ext_vector_type(4))) float;

enum { F_INRELU = 1, F_OUTRELU = 2, F_RES = 4 };

struct TapSet { int dy[16]; int dx[16]; int wi[16]; };

__device__ __forceinline__ unsigned int relu_pk(unsigned int v) {
    unsigned int m = ((v & 0x80008000u) >> 15) * 0xFFFFu;
    return v & ~m;
}
__device__ __forceinline__ unsigned int mask_by(unsigned int v, unsigned int h) {
    unsigned int m = ((h & 0x80008000u) >> 15) * 0xFFFFu;
    return v & ~m;
}
// XCD-chunked swizzle: consecutive logical tiles land on the SAME XCD's L2
// (default dispatch round-robins blockIdx across 8 XCDs). Requires n % 8 == 0.
__device__ __forceinline__ int xcd_swz(int bx, int n) {
    return (bx & 7) * (n >> 3) + (bx >> 3);
}

// ---------------- weight pre-pack: bf16 (decoder) ----------------
__global__ void pack_w_k(const float* __restrict__ w, bf16* __restrict__ dst,
                         int Ci, int Co, int BN, TapSet taps, int total)
{
    int idx = blockIdx.x * 256 + threadIdx.x;
    if (idx >= total) return;
    int j  = idx & 7;
    int r1 = idx >> 3;
    int nl = r1 % BN;
    int r2 = r1 / BN;
    int q  = r2 & 3;
    int cb = r2 >> 2;
    int nblocks = Co / BN;
    int c  = cb / nblocks;
    int nb = cb - c * nblocks;
    int cpt = Ci >> 5;
    int tap = c / cpt;
    int ci  = (c - tap * cpt) * 32 + q * 8 + j;
    int n   = nb * BN + nl;
    dst[idx] = __float2bfloat16(w[(size_t)(taps.wi[tap] * Ci + ci) * Co + n]);
}

// ---------------- weight pre-pack: fp16 hi/lo split (encoder) ----------------
__global__ void pack_w2_k(const float* __restrict__ w, __half* __restrict__ dst,
                          int Ci, int Co, int BN, TapSet taps, int total)
{
    int idx = blockIdx.x * 256 + threadIdx.x;
    if (idx >= total) return;
    int j  = idx & 7;
    int r1 = idx >> 3;
    int nl = r1 % BN;
    int r2 = r1 / BN;
    int q  = r2 & 3;
    int cb = r2 >> 2;
    int nblocks = Co / BN;
    int c  = cb / nblocks;
    int nb = cb - c * nblocks;
    int cpt = Ci >> 5;
    int tap = c / cpt;
    int ci  = (c - tap * cpt) * 32 + q * 8 + j;
    int n   = nb * BN + nl;
    float v = w[(size_t)(taps.wi[tap] * Ci + ci) * Co + n];
    __half h = __float2half(v);
    __half l = __float2half((v - __half2float(h)) * 2048.0f);
    size_t base = (size_t)cb * (BN * 64) + (q * BN + nl) * 8 + j;
    dst[base] = h;
    dst[base + BN * 32] = l;
}

// ---------------- dt2 weight pack: (4,4,64,3) -> per-parity K=256, N=16 (pad), hi/lo ----
__global__ void pack_wdt2_k(const float* __restrict__ w, __half* __restrict__ dst)
{
    int idx = blockIdx.x * 256 + threadIdx.x;   // 16384
    if (idx >= 16384) return;
    int parity = idx >> 12;
    int r0 = idx & 4095;
    int j  = r0 & 7;
    int r1 = r0 >> 3;
    int nl = r1 & 15;
    int r2 = r1 >> 4;
    int q  = r2 & 3;
    int cb = r2 >> 2;                 // 0..7
    int tap = cb >> 1;
    int cc  = cb & 1;
    int ci  = cc * 32 + q * 8 + j;
    int n   = nl;
    int py = parity >> 1, px = parity & 1;
    int ty = tap >> 1, tx = tap & 1;
    int wi = (py + 2 * ty) * 4 + (px + 2 * tx);
    float v = (n < 3) ? w[(size_t)(wi * 64 + ci) * 3 + n] : 0.f;
    __half h = __float2half(v);
    __half l = __float2half((v - __half2float(h)) * 2048.0f);
    size_t base = (size_t)parity * 8192 + cb * 1024 + (q * 16 + nl) * 8 + j;
    dst[base] = h;
    dst[base + 512] = l;
}

// ---------------- enc1 weight pack: (4,4,3,64) -> K=64 (4th ch zero), hi/lo ----------------
__global__ void pack_we1_k(const float* __restrict__ w, __half* __restrict__ dst)
{
    int idx = blockIdx.x * 256 + threadIdx.x;   // 2*4*64*8 = 4096
    if (idx >= 4096) return;
    int j  = idx & 7;
    int r1 = idx >> 3;
    int nl = r1 & 63;
    int r2 = r1 >> 6;
    int q  = r2 & 3;
    int c  = r2 >> 2;                 // chunk 0/1
    int k  = c * 32 + q * 8 + j;
    int tap = k >> 2, ci = k & 3;
    float v = (ci < 3) ? w[(size_t)(tap * 3 + ci) * 64 + nl] : 0.f;
    __half h = __float2half(v);
    __half l = __float2half((v - __half2float(h)) * 2048.0f);
    size_t base = (size_t)c * 4096 + (q * 64 + nl) * 8 + j;
    dst[base] = h;
    dst[base + 2048] = l;
}

// ---------------- x pad: (16,256,256,3) fp32 -> (.,4) fp16 hi/lo ----------------
__global__ __launch_bounds__(256) void pad_x_k(
    const float* __restrict__ x, __half* __restrict__ xh, __half* __restrict__ xl)
{
    int pix = blockIdx.x * 256 + threadIdx.x;   // 1048576
    const float* ip = x + (size_t)pix * 3;
    float v0 = ip[0], v1 = ip[1], v2 = ip[2];
    unsigned short hb[4], lb[4];
    float vv[4] = {v0, v1, v2, 0.f};
#pragma unroll
    for (int i = 0; i < 4; ++i) {
        __half h = __float2half(vv[i]);
        hb[i] = __half_as_ushort(h);
        lb[i] = __half_as_ushort(__float2half((vv[i] - __half2float(h)) * 2048.0f));
    }
    uint2 hv = make_uint2((unsigned)hb[0] | ((unsigned)hb[1] << 16),
                          (unsigned)hb[2] | ((unsigned)hb[3] << 16));
    uint2 lv = make_uint2((unsigned)lb[0] | ((unsigned)lb[1] << 16),
                          (unsigned)lb[2] | ((unsigned)lb[3] << 16));
    *(uint2*)(xh + (size_t)pix * 4) = hv;
    *(uint2*)(xl + (size_t)pix * 4) = lv;
}

// ---------------- enc1: 4x4 s2, 4ch padded, fp16-split MFMA ----------------
__global__ __launch_bounds__(256) void enc1_mfma_k(
    const __half* __restrict__ xh, const __half* __restrict__ xl,
    const __half* __restrict__ wp, const float* __restrict__ bias,
    __half* __restrict__ oh, __half* __restrict__ ol)
{
    __shared__ __align__(16) short Ash[64 * 32];
    __shared__ __align__(16) short Asl[64 * 32];
    __shared__ __align__(16) short Bsh[64 * 32];
    __shared__ __align__(16) short Bsl[64 * 32];

    const int tid = threadIdx.x;
    const int m0 = xcd_swz(blockIdx.x, 4096) * 64;

    const int am = tid >> 2;
    const int aq = tid & 3;
    const int gm  = m0 + am;
    const int nn_ = gm >> 14;            // 128*128 pixels/image
    const int rr_ = gm & 16383;
    const int iy0 = (rr_ >> 7) * 2 - 1;
    const int ix0 = (rr_ & 127) * 2 - 1;

    const int lane = tid & 63;
    const int wv4 = tid >> 6;
    const int wm = (wv4 & 1) * 32;
    const int wn = (wv4 >> 1) * 32;
    const int lm = lane & 15, lq = lane >> 4;

    frag_cd accA[2][2], accB[2][2];
#pragma unroll
    for (int i = 0; i < 2; ++i)
#pragma unroll
        for (int j = 0; j < 2; ++j)
#pragma unroll
            for (int r = 0; r < 4; ++r) { accA[i][j][r] = 0.f; accB[i][j][r] = 0.f; }

#pragma unroll
    for (int c = 0; c < 2; ++c) {
        const int tap = c * 8 + aq * 2;
        const int ky = tap >> 2, kx = tap & 3;
        const int iy = iy0 + ky;
        const int ix = ix0 + kx;
        uint2 h0 = make_uint2(0u, 0u), h1 = h0, l0 = h0, l1 = h0;
        if (iy >= 0 && iy < 256) {
            const size_t rowb = (size_t)(nn_ * 256 + iy) * 256;
            if (ix >= 0 && ix < 256) {
                h0 = *(const uint2*)(xh + (rowb + ix) * 4);
                l0 = *(const uint2*)(xl + (rowb + ix) * 4);
            }
            if (ix + 1 >= 0 && ix + 1 < 256) {
                h1 = *(const uint2*)(xh + (rowb + ix + 1) * 4);
                l1 = *(const uint2*)(xl + (rowb + ix + 1) * 4);
            }
        }
        __syncthreads();
        *(uint4*)&Ash[(aq * 64 + am) * 8] = make_uint4(h0.x, h0.y, h1.x, h1.y);
        *(uint4*)&Asl[(aq * 64 + am) * 8] = make_uint4(l0.x, l0.y, l1.x, l1.y);
        {
            const __half* wc = wp + (size_t)c * 4096;
            *(uint4*)&Bsh[tid * 8] = *(const uint4*)(wc + tid * 8);
            *(uint4*)&Bsl[tid * 8] = *(const uint4*)(wc + 2048 + tid * 8);
        }
        __syncthreads();

        f16x8 afh[2], afl[2], bfh[2], bfl[2];
#pragma unroll
        for (int i = 0; i < 2; ++i) {
            afh[i] = *(const f16x8*)&Ash[(lq * 64 + wm + i * 16 + lm) * 8];
            afl[i] = *(const f16x8*)&Asl[(lq * 64 + wm + i * 16 + lm) * 8];
        }
#pragma unroll
        for (int j = 0; j < 2; ++j) {
            bfh[j] = *(const f16x8*)&Bsh[(lq * 64 + wn + j * 16 + lm) * 8];
            bfl[j] = *(const f16x8*)&Bsl[(lq * 64 + wn + j * 16 + lm) * 8];
        }
#pragma unroll
        for (int i = 0; i < 2; ++i)
#pragma unroll
            for (int j = 0; j < 2; ++j) {
                accA[i][j] = __builtin_amdgcn_mfma_f32_16x16x32_f16(afh[i], bfh[j], accA[i][j], 0, 0, 0);
                accB[i][j] = __builtin_amdgcn_mfma_f32_16x16x32_f16(afh[i], bfl[j], accB[i][j], 0, 0, 0);
                accB[i][j] = __builtin_amdgcn_mfma_f32_16x16x32_f16(afl[i], bfh[j], accB[i][j], 0, 0, 0);
            }
    }

    const float s = 1.0f / 2048.0f;
#pragma unroll
    for (int j = 0; j < 2; ++j) {
        const int n_g = wn + j * 16 + lm;
        const float bv = bias[n_g];
#pragma unroll
        for (int i = 0; i < 2; ++i) {
#pragma unroll
            for (int r = 0; r < 4; ++r) {
                const int m_g = m0 + wm + i * 16 + lq * 4 + r;
                const size_t ob = (size_t)m_g * 64 + n_g;
                float v = accA[i][j][r] + accB[i][j][r] * s + bv;
                v = fmaxf(v, 0.f);
                __half h = __float2half(v);
                oh[ob] = h;
                ol[ob] = __float2half((v - __half2float(h)) * 2048.0f);
            }
        }
    }
}

// ---------------- fp16-split MFMA implicit-GEMM conv (encoder) ----------------
// BN=128: one block covers ALL output channels -> A staged/fetched once (was 2x
// via gridDim.y=2) and 24 MFMA per barrier-pair (was 12).  Wave tile 32x64.
template<int BN>
__global__ __launch_bounds__(256) void conv_mfma2_k(
    const __half* __restrict__ ah, const __half* __restrict__ al,
    const __half* __restrict__ wp, const float* __restrict__ bias,
    float* __restrict__ out, __half* __restrict__ oh, __half* __restrict__ ol,
    const __half* __restrict__ rh, const __half* __restrict__ rl,
    int IH, int IW, int Ci, int Co, int sy_in,
    TapSet taps, int ntaps, int flags)
{
    __shared__ __align__(16) short Ash[64 * 32];
    __shared__ __align__(16) short Asl[64 * 32];
    __shared__ __align__(16) short Bsh[BN * 32];
    __shared__ __align__(16) short Bsl[BN * 32];

    const int tid = threadIdx.x;
    const int m0 = xcd_swz(blockIdx.x, gridDim.x) * 64;
    const int n0 = blockIdx.y * BN;

    const int am = tid >> 2;
    const int aq = tid & 3;
    const int gm  = m0 + am;
    const int nn_ = gm >> 12;
    const int rr_ = gm & 4095;
    const int oy_ = (rr_ >> 6) * sy_in;
    const int ox_ = (rr_ & 63) * sy_in;

    const int lane = tid & 63;
    const int wv4 = tid >> 6;
    constexpr int MT = (BN >= 64) ? 2 : 1;
    constexpr int NT = (BN == 128) ? 4 : 2;
    const int wm = (BN >= 64) ? (wv4 & 1) * 32 : wv4 * 16;
    const int wn = (BN == 128) ? (wv4 >> 1) * 64 : ((BN == 64) ? (wv4 >> 1) * 32 : 0);
    const int lm = lane & 15, lq = lane >> 4;
    constexpr int NLOAD = BN * 32 / 8;

    frag_cd accA[MT][NT], accB[MT][NT];
#pragma unroll
    for (int i = 0; i < MT; ++i)
#pragma unroll
        for (int j = 0; j < NT; ++j)
#pragma unroll
            for (int r = 0; r < 4; ++r) { accA[i][j][r] = 0.f; accB[i][j][r] = 0.f; }

    const int cpt = Ci >> 5;
    const int nch = ntaps * cpt;
    const bool inrelu = (flags & F_INRELU) != 0;

    int tap = 0, cc = 0, ci0 = 0;
    for (int c = 0; c < nch; ++c) {
        const int iy = oy_ + taps.dy[tap];
        const int ix = ox_ + taps.dx[tap];
        uint4 avh = make_uint4(0u, 0u, 0u, 0u);
        uint4 avl = make_uint4(0u, 0u, 0u, 0u);
        if (iy >= 0 && iy < IH && ix >= 0 && ix < IW) {
            const size_t off = (size_t)((nn_ * IH + iy) * IW + ix) * Ci + ci0 + aq * 8;
            avh = *(const uint4*)(ah + off);
            avl = *(const uint4*)(al + off);
        }
        if (inrelu) {
            avl.x = mask_by(avl.x, avh.x); avl.y = mask_by(avl.y, avh.y);
            avl.z = mask_by(avl.z, avh.z); avl.w = mask_by(avl.w, avh.w);
            avh.x = relu_pk(avh.x); avh.y = relu_pk(avh.y);
            avh.z = relu_pk(avh.z); avh.w = relu_pk(avh.w);
        }
        uint4 bvh0, bvl0, bvh1, bvl1;
        {
            const __half* wc = wp + (size_t)(c * gridDim.y + blockIdx.y) * (BN * 64);
            if constexpr (BN == 128) {
                bvh0 = *(const uint4*)(wc + tid * 8);
                bvh1 = *(const uint4*)(wc + (256 + tid) * 8);
                bvl0 = *(const uint4*)(wc + BN * 32 + tid * 8);
                bvl1 = *(const uint4*)(wc + BN * 32 + (256 + tid) * 8);
            } else if (tid < NLOAD) {
                bvh0 = *(const uint4*)(wc + tid * 8);
                bvl0 = *(const uint4*)(wc + BN * 32 + tid * 8);
            }
        }

        __syncthreads();
        *(uint4*)&Ash[(aq * 64 + am) * 8] = avh;
        *(uint4*)&Asl[(aq * 64 + am) * 8] = avl;
        if constexpr (BN == 128) {
            *(uint4*)&Bsh[tid * 8] = bvh0;
            *(uint4*)&Bsh[(256 + tid) * 8] = bvh1;
            *(uint4*)&Bsl[tid * 8] = bvl0;
            *(uint4*)&Bsl[(256 + tid) * 8] = bvl1;
        } else if (tid < NLOAD) {
            *(uint4*)&Bsh[tid * 8] = bvh0;
            *(uint4*)&Bsl[tid * 8] = bvl0;
        }
        __syncthreads();

        f16x8 afh[MT], afl[MT], bfh[NT], bfl[NT];
#pragma unroll
        for (int i = 0; i < MT; ++i) {
            afh[i] = *(const f16x8*)&Ash[(lq * 64 + wm + i * 16 + lm) * 8];
            afl[i] = *(const f16x8*)&Asl[(lq * 64 + wm + i * 16 + lm) * 8];
        }
#pragma unroll
        for (int j = 0; j < NT; ++j) {
            bfh[j] = *(const f16x8*)&Bsh[(lq * BN + wn + j * 16 + lm) * 8];
            bfl[j] = *(const f16x8*)&Bsl[(lq * BN + wn + j * 16 + lm) * 8];
        }
#pragma unroll
        for (int i = 0; i < MT; ++i)
#pragma unroll
            for (int j = 0; j < NT; ++j) {
                accA[i][j] = __builtin_amdgcn_mfma_f32_16x16x32_f16(afh[i], bfh[j], accA[i][j], 0, 0, 0);
                accB[i][j] = __builtin_amdgcn_mfma_f32_16x16x32_f16(afh[i], bfl[j], accB[i][j], 0, 0, 0);
                accB[i][j] = __builtin_amdgcn_mfma_f32_16x16x32_f16(afl[i], bfh[j], accB[i][j], 0, 0, 0);
            }

        ci0 += 32;
        if (++cc == cpt) { cc = 0; ci0 = 0; ++tap; }
    }

    const float s = 1.0f / 2048.0f;
#pragma unroll
    for (int j = 0; j < NT; ++j) {
        const int n_g = n0 + wn + j * 16 + lm;
        const float bv = bias ? bias[n_g] : 0.f;
#pragma unroll
        for (int i = 0; i < MT; ++i) {
#pragma unroll
            for (int r = 0; r < 4; ++r) {
                const int m_g = m0 + wm + i * 16 + lq * 4 + r;
                const size_t ob = (size_t)m_g * Co + n_g;
                float v = accA[i][j][r] + accB[i][j][r] * s + bv;
                if (flags & F_RES)
                    v += __half2float(rh[ob]) + __half2float(rl[ob]) * s;
                if (flags & F_OUTRELU) v = fmaxf(v, 0.f);
                if (out) out[ob] = v;
                if (oh) {
                    __half h = __float2half(v);
                    oh[ob] = h;
                    ol[ob] = __float2half((v - __half2float(h)) * 2048.0f);
                }
            }
        }
    }
}

// ---------------- bf16 MFMA implicit-GEMM conv (decoder) ----------------
template<int BN>
__global__ __launch_bounds__(256) void conv_mfma_k(
    const bf16* __restrict__ a, const bf16* __restrict__ wp,
    const float* __restrict__ bias,
    float* __restrict__ out, bf16* __restrict__ out_bf,
    const float* __restrict__ res,
    int Ci, int Co, int OHf, int OWf, int sy_out, int py, int px,
    TapSet taps, int ntaps, int flags)
{
    __shared__ __align__(16) short As[64 * 32];
    __shared__ __align__(16) short Bs[BN * 32];

    const int tid = threadIdx.x;
    const int m0 = xcd_swz(blockIdx.x, gridDim.x) * 64;
    const int n0 = blockIdx.y * BN;

    const int am = tid >> 2;
    const int aq = tid & 3;
    const int gm  = m0 + am;
    const int nn_ = gm >> 12;
    const int rr_ = gm & 4095;
    const int oy_ = rr_ >> 6;
    const int ox_ = rr_ & 63;

    const int lane = tid & 63;
    const int wv4 = tid >> 6;
    constexpr int MT = (BN >= 64) ? 2 : 1;
    constexpr int NT = (BN == 128) ? 4 : 2;
    const int wm = (BN >= 64) ? (wv4 & 1) * 32 : wv4 * 16;
    const int wn = (BN == 128) ? (wv4 >> 1) * 64 : ((BN == 64) ? (wv4 >> 1) * 32 : 0);
    const int lm = lane & 15, lq = lane >> 4;
    constexpr int NLOAD = BN * 32 / 8;

    frag_cd acc[MT][NT];
#pragma unroll
    for (int i = 0; i < MT; ++i)
#pragma unroll
        for (int j = 0; j < NT; ++j)
#pragma unroll
            for (int r = 0; r < 4; ++r) acc[i][j][r] = 0.f;

    const int cpt = Ci >> 5;
    const int nch = ntaps * cpt;
    const bool inrelu = (flags & F_INRELU) != 0;

    int tap = 0, cc = 0, ci0 = 0;
    for (int c = 0; c < nch; ++c) {
        const int iy = oy_ + taps.dy[tap];
        const int ix = ox_ + taps.dx[tap];
        uint4 av = make_uint4(0u, 0u, 0u, 0u);
        if (iy >= 0 && iy < 64 && ix >= 0 && ix < 64)
            av = *(const uint4*)(a + (size_t)((nn_ * 64 + iy) * 64 + ix) * Ci + ci0 + aq * 8);
        if (inrelu) {
            av.x = relu_pk(av.x); av.y = relu_pk(av.y);
            av.z = relu_pk(av.z); av.w = relu_pk(av.w);
        }
        uint4 bv0, bv1;
        {
            const bf16* wc = wp + ((size_t)c * gridDim.y + blockIdx.y) * (BN * 32);
            if constexpr (BN == 128) {
                bv0 = *(const uint4*)(wc + tid * 8);
                bv1 = *(const uint4*)(wc + (256 + tid) * 8);
            } else if (tid < NLOAD) {
                bv0 = *(const uint4*)(wc + tid * 8);
            }
        }

        __syncthreads();
        *(uint4*)&As[(aq * 64 + am) * 8] = av;
        if constexpr (BN == 128) {
            *(uint4*)&Bs[tid * 8] = bv0;
            *(uint4*)&Bs[(256 + tid) * 8] = bv1;
        } else if (tid < NLOAD) {
            *(uint4*)&Bs[tid * 8] = bv0;
        }
        __syncthreads();

        frag_ab af[MT], bfr[NT];
#pragma unroll
        for (int i = 0; i < MT; ++i)
            af[i] = *(const frag_ab*)&As[(lq * 64 + wm + i * 16 + lm) * 8];
#pragma unroll
        for (int j = 0; j < NT; ++j)
            bfr[j] = *(const frag_ab*)&Bs[(lq * BN + wn + j * 16 + lm) * 8];
#pragma unroll
        for (int i = 0; i < MT; ++i)
#pragma unroll
            for (int j = 0; j < NT; ++j)
                acc[i][j] = __builtin_amdgcn_mfma_f32_16x16x32_bf16(af[i], bfr[j], acc[i][j], 0, 0, 0);

        ci0 += 32;
        if (++cc == cpt) { cc = 0; ci0 = 0; ++tap; }
    }

#pragma unroll
    for (int j = 0; j < NT; ++j) {
        const int n_g = n0 + wn + j * 16 + lm;
        const float bv = bias ? bias[n_g] : 0.f;
#pragma unroll
        for (int i = 0; i < MT; ++i) {
#pragma unroll
            for (int r = 0; r < 4; ++r) {
                const int m_g = m0 + wm + i * 16 + lq * 4 + r;
                const int nn2 = m_g >> 12;
                const int rr2 = m_g & 4095;
                const int oy = (rr2 >> 6) * sy_out + py;
                const int ox = (rr2 & 63) * sy_out + px;
                const size_t ob = ((size_t)(nn2 * OHf + oy) * OWf + ox) * Co + n_g;
                float v = acc[i][j][r] + bv;
                if (flags & F_RES)     v += res[ob];
                if (flags & F_OUTRELU) v = fmaxf(v, 0.f);
                if (out)    out[ob]    = v;
                if (out_bf) out_bf[ob] = __float2bfloat16(v);
            }
        }
    }
}

// ---------------- dt2: convT 4x4 s2, 64->3 via fp16-split MFMA -------------------
// Round-10 PMC: dt2 is LDS-ISSUE-bound — per chunk ~26 wave-level b128 LDS ops
// (8 A-writes + 2 B-writes + 16 frag reads), each inherently ~8 bank-cycles
// (64 lanes x 16B = 1KB through 128B/clk LDS) -> ~44us of the 92.  Convert
// cost irrelevant (pkrtz was dur-neutral).  Fix: remove B from LDS entirely —
// each lane's B address (wpar + c*1024 + lane*8) is block-invariant -> L1-hot;
// preload all 8 chunks x hi/lo into 64 VGPRs before the loop (this exact path
// was verified correct in r7-r9).  Cuts LDS to 16 wave-ops/chunk (-38%).
// Loop fully unrolled so bh[c]/bl[c] stay register-resident (rule #20).
__global__ __launch_bounds__(256) void dt2_mfma_k(
    const float* __restrict__ in,      // A1: (16,128,128,64) fp32, relu'd
    const __half* __restrict__ wp,     // packed per-parity weights (4 x 8192 halves)
    const float* __restrict__ bias,    // 3
    float* __restrict__ out)           // (16,256,256,3)
{
    __shared__ __align__(16) short Ash[64 * 32];
    __shared__ __align__(16) short Asl[64 * 32];

    const int tid = threadIdx.x;
    const int bx  = xcd_swz(blockIdx.x, 16384);   // parity quads stay on one XCD
    const int par = bx & 3;
    const int m0  = (bx >> 2) * 64;
    const int py = par >> 1, px = par & 1;

    const int am = tid >> 2;
    const int aq = tid & 3;
    const int gm  = m0 + am;
    const int nn_ = gm >> 14;            // image
    const int rr_ = gm & 16383;
    const int r_  = rr_ >> 7;            // 0..127
    const int c_  = rr_ & 127;

    const int lane = tid & 63;
    const int wv4 = tid >> 6;
    const int wm = wv4 * 16;
    const int lm = lane & 15, lq = lane >> 4;

    // ---- B hi/lo fragments for all 8 chunks -> 64 VGPRs (L1-hot; same address
    // every block).  Verified-correct addressing from r7: element lane=lq*16+lm.
    const __half* wpar = wp + (size_t)par * 8192;
    f16x8 bh[8], bl[8];
#pragma unroll
    for (int c = 0; c < 8; ++c) {
        const __half* wc = wpar + c * 1024 + lane * 8;
        bh[c] = *(const f16x8*)wc;
        bl[c] = *(const f16x8*)(wc + 512);
    }

    frag_cd accA, accB;
#pragma unroll
    for (int r = 0; r < 4; ++r) { accA[r] = 0.f; accB[r] = 0.f; }

#pragma unroll
    for (int c = 0; c < 8; ++c) {
        const int tap = c >> 1;
        const int iy = r_ + py + (tap >> 1) - 1;
        const int ix = c_ + px + (tap & 1) - 1;
        const int ci0 = (c & 1) * 32;
        uint4 hi = make_uint4(0u, 0u, 0u, 0u);
        uint4 lo = make_uint4(0u, 0u, 0u, 0u);
        if ((unsigned)iy < 128u && (unsigned)ix < 128u) {
            const float* ip = in + (size_t)((nn_ * 128 + iy) * 128 + ix) * 64 + ci0 + aq * 8;
            const float4 v0 = *(const float4*)ip;
            const float4 v1 = *(const float4*)(ip + 4);
            const float vv[8] = {v0.x, v0.y, v0.z, v0.w, v1.x, v1.y, v1.z, v1.w};
            union { hf16x2 p[4]; uint4 u; } uh, ul;
#pragma unroll
            for (int i = 0; i < 4; ++i) {
                hf16x2 h = __builtin_amdgcn_cvt_pkrtz(vv[2 * i], vv[2 * i + 1]);
                uh.p[i] = h;
                ul.p[i] = __builtin_amdgcn_cvt_pkrtz((vv[2 * i]     - (float)h[0]) * 2048.f,
                                                     (vv[2 * i + 1] - (float)h[1]) * 2048.f);
            }
            hi = uh.u;
            lo = ul.u;
        }

        __syncthreads();
        *(uint4*)&Ash[(aq * 64 + am) * 8] = hi;
        *(uint4*)&Asl[(aq * 64 + am) * 8] = lo;
        __syncthreads();

        const f16x8 afh = *(const f16x8*)&Ash[(lq * 64 + wm + lm) * 8];
        const f16x8 afl = *(const f16x8*)&Asl[(lq * 64 + wm + lm) * 8];
        accA = __builtin_amdgcn_mfma_f32_16x16x32_f16(afh, bh[c], accA, 0, 0, 0);
        accB = __builtin_amdgcn_mfma_f32_16x16x32_f16(afh, bl[c], accB, 0, 0, 0);
        accB = __builtin_amdgcn_mfma_f32_16x16x32_f16(afl, bh[c], accB, 0, 0, 0);
    }

    const float s = 1.0f / 2048.0f;
    if (lm < 3) {
        const float bv = bias[lm];
#pragma unroll
        for (int r = 0; r < 4; ++r) {
            const int m_g = m0 + wm + lq * 4 + r;
            const int nn2 = m_g >> 14;
            const int rr2 = m_g & 16383;
            const int oy = (rr2 >> 7) * 2 + py;
            const int ox = (rr2 & 127) * 2 + px;
            out[((size_t)(nn2 * 256 + oy) * 256 + ox) * 3 + lm] = accA[r] + accB[r] * s + bv;
        }
    }
}

// ---------------- VQ ----------------
__global__ void enorm_k(const float* __restrict__ emb, float* __restrict__ en) {
    int k = blockIdx.x * 256 + threadIdx.x;
    if (k >= 512) return;
    const float4* e = (const float4*)(emb + k * 128);
    float s = 0.f;
    for (int i = 0; i < 32; ++i) {
        float4 v = e[i];
        s += v.x * v.x + v.y * v.y + v.z * v.z + v.w * v.w;
    }
    en[k] = s;
}

__global__ void pack_emb_k(const float* __restrict__ emb, __half* __restrict__ dst)
{
    int idx = blockIdx.x * 256 + threadIdx.x;   // 65536
    int k = idx & 127;
    int n = idx >> 7;
    float v = emb[idx];
    __half h = __float2half(v);
    __half l = __float2half((v - __half2float(h)) * 2048.0f);
    int nb = n >> 6, nl = n & 63;
    int ch = k >> 5, q = (k >> 3) & 3, j = k & 7;
    size_t base = (size_t)(nb * 4 + ch) * 4096 + (q * 64 + nl) * 8 + j;
    dst[base] = h;
    dst[base + 2048] = l;
}

__global__ __launch_bounds__(256) void vq_mfma_k(
    const __half* __restrict__ fh, const __half* __restrict__ fl,
    const __half* __restrict__ pe, const float* __restrict__ en,
    const float* __restrict__ emb, float* __restrict__ q, bf16* __restrict__ qb)
{
    __shared__ __align__(16) short Ash[64 * 128];
    __shared__ __align__(16) short Asl[64 * 128];
    __shared__ int sel[64];

    const int tid  = threadIdx.x;
    const int pos0 = blockIdx.x * 64;

    {
        const int am = tid >> 2;
        const int aq = tid & 3;
#pragma unroll
        for (int ch = 0; ch < 4; ++ch) {
            const size_t off = (size_t)(pos0 + am) * 128 + ch * 32 + aq * 8;
            uint4 vh = *(const uint4*)(fh + off);
            uint4 vl = *(const uint4*)(fl + off);
            *(uint4*)&Ash[((ch * 4 + aq) * 64 + am) * 8] = vh;
            *(uint4*)&Asl[((ch * 4 + aq) * 64 + am) * 8] = vl;
        }
    }
    __syncthreads();

    const int lane = tid & 63;
    const int w    = tid >> 6;
    const int lm = lane & 15, lq = lane >> 4;
    const int mbase = w * 16;
    const float s = 1.0f / 2048.0f;

    float best[4] = {3.4e38f, 3.4e38f, 3.4e38f, 3.4e38f};
    int   bidx[4] = {0, 0, 0, 0};

    f16x8 ah[4], alv[4];
#pragma unroll
    for (int ch = 0; ch < 4; ++ch) {
        ah[ch]  = *(const f16x8*)&Ash[((ch * 4 + lq) * 64 + mbase + lm) * 8];
        alv[ch] = *(const f16x8*)&Asl[((ch * 4 + lq) * 64 + mbase + lm) * 8];
    }

    for (int nb = 0; nb < 8; ++nb) {
        frag_cd accA[4], accB[4];
#pragma unroll
        for (int j = 0; j < 4; ++j)
#pragma unroll
            for (int r = 0; r < 4; ++r) { accA[j][r] = 0.f; accB[j][r] = 0.f; }

#pragma unroll
        for (int ch = 0; ch < 4; ++ch) {
            const __half* base = pe + (size_t)(nb * 4 + ch) * 4096;
            f16x8 bh[4], bl[4];
#pragma unroll
            for (int j = 0; j < 4; ++j) {
                const int o = (lq * 64 + j * 16 + lm) * 8;
                bh[j] = *(const f16x8*)(base + o);
                bl[j] = *(const f16x8*)(base + 2048 + o);
            }
#pragma unroll
            for (int j = 0; j < 4; ++j) {
                accA[j] = __builtin_amdgcn_mfma_f32_16x16x32_f16(ah[ch], bh[j], accA[j], 0, 0, 0);
                accB[j] = __builtin_amdgcn_mfma_f32_16x16x32_f16(ah[ch], bl[j], accB[j], 0, 0, 0);
                accB[j] = __builtin_amdgcn_mfma_f32_16x16x32_f16(alv[ch], bh[j], accB[j], 0, 0, 0);
            }
        }

#pragma unroll
        for (int j = 0; j < 4; ++j) {
            const int code = nb * 64 + j * 16 + lm;
            const float ec = en[code];
#pragma unroll
            for (int r = 0; r < 4; ++r) {
                float dot = accA[j][r] + accB[j][r] * s;
                float d = fmaf(dot, -2.f, ec);
                if (d < best[r]) { best[r] = d; bidx[r] = code; }
            }
        }
    }

#pragma unroll
    for (int r = 0; r < 4; ++r) {
        float d = best[r]; int ix = bidx[r];
#pragma unroll
        for (int m = 1; m < 16; m <<= 1) {
            float d2 = __shfl_xor(d, m);
            int   x2 = __shfl_xor(ix, m);
            if (d2 < d || (d2 == d && x2 < ix)) { d = d2; ix = x2; }
        }
        if (lm == 0) sel[mbase + lq * 4 + r] = ix;
    }
    __syncthreads();

#pragma unroll
    for (int jj = 0; jj < 32; ++jj) {
        int id = jj * 256 + tid;
        int p = id >> 7, k = id & 127;
        float v = emb[(size_t)sel[p] * 128 + k];
        q[(size_t)(pos0 + p) * 128 + k]  = v;
        qb[(size_t)(pos0 + p) * 128 + k] = __float2bfloat16(v);
    }
}

// ---------------- host ----------------
static TapSet conv_taps(int KH, int KW, int pad) {
    TapSet t{};
    for (int ky = 0; ky < KH; ++ky)
        for (int kx = 0; kx < KW; ++kx) {
            int i = ky * KW + kx;
            t.dy[i] = ky - pad; t.dx[i] = kx - pad; t.wi[i] = i;
        }
    return t;
}

static TapSet convt_taps(int py, int px) {
    TapSet t{};
    for (int ty = 0; ty < 2; ++ty)
        for (int tx = 0; tx < 2; ++tx) {
            int i = ty * 2 + tx;
            t.dy[i] = py + ty - 1;
            t.dx[i] = px + tx - 1;
            t.wi[i] = (py + 2 * ty) * 4 + (px + 2 * tx);
        }
    return t;
}

extern "C" void kernel_launch(void* const* d_in, const int* in_sizes, int n_in,
                              void* d_out, int out_size, void* d_ws, size_t ws_size,
                              hipStream_t stream)
{
    const float* x       = (const float*)d_in[0];
    const float* emb     = (const float*)d_in[1];
    const float* enc_w1  = (const float*)d_in[2];
    const float* enc_b1  = (const float*)d_in[3];
    const float* enc_w2  = (const float*)d_in[4];
    const float* enc_b2  = (const float*)d_in[5];
    const float* enc_w3  = (const float*)d_in[6];
    const float* enc_b3  = (const float*)d_in[7];
    const float* erb1_w1 = (const float*)d_in[8];
    const float* erb1_w2 = (const float*)d_in[9];
    const float* erb2_w1 = (const float*)d_in[10];
    const float* erb2_w2 = (const float*)d_in[11];
    const float* dec_w   = (const float*)d_in[12];
    const float* dec_b   = (const float*)d_in[13];
    const float* drb1_w1 = (const float*)d_in[14];
    const float* drb1_w2 = (const float*)d_in[15];
    const float* drb2_w1 = (const float*)d_in[16];
    const float* drb2_w2 = (const float*)d_in[17];
    const float* dt1_w   = (const float*)d_in[18];
    const float* dt1_b   = (const float*)d_in[19];
    const float* dt2_w   = (const float*)d_in[20];
    const float* dt2_b   = (const float*)d_in[21];

    char* wsb = (char*)d_ws;
    __half* H1 = (__half*)wsb;                           // 33.55 MB
    __half* L1 = (__half*)(wsb + (size_t)33554432);      // 33.55 MB
    __half* H2 = (__half*)(wsb + (size_t)67108864);      // 16.78 MB
    __half* L2 = (__half*)(wsb + (size_t)83886080);      // 16.78 MB
    // x padded planes alias the (not-yet-written) H2/L2 region
    __half* Xh = (__half*)(wsb + (size_t)67108864);      // 8.39 MB
    __half* Xl = (__half*)(wsb + (size_t)75497472);      // 8.39 MB
    __half* H3 = (__half*)wsb;
    __half* L3 = (__half*)(wsb + (size_t)16777216);
    __half* H4 = (__half*)(wsb + (size_t)33554432);
    __half* L4 = (__half*)(wsb + (size_t)50331648);
    __half* Ht = (__half*)(wsb + (size_t)100663296);     // 4.19 MB
    __half* Lt = (__half*)(wsb + (size_t)104857600);     // 4.19 MB
    float*  EN = (float*)(wsb + (size_t)109051904);      // 2 KB
    __half* Fh = (__half*)wsb;
    __half* Fl = (__half*)(wsb + (size_t)16777216);
    bf16* Qb  = (bf16*)(wsb + (size_t)67108864);
    bf16* Db  = (bf16*)(wsb + (size_t)83886080);
    bf16* Y1b = Qb;
    bf16* Y2b = Db;
    bf16* Tb  = (bf16*)(wsb + (size_t)100663296);
    float* Y0 = (float*)wsb;
    float* Y1 = (float*)(wsb + (size_t)33554432);
    float* A1 = (float*)wsb;
    char* pk = wsb + (size_t)109056000;
    bf16* Pdec  = (bf16*)pk;  pk += 147456 * 2;
    bf16* Pd1w1 = (bf16*)pk;  pk += 36864 * 2;
    bf16* Pd1w2 = (bf16*)pk;  pk += 4096 * 2;
    bf16* Pd2w1 = (bf16*)pk;  pk += 36864 * 2;
    bf16* Pd2w2 = (bf16*)pk;  pk += 4096 * 2;
    bf16* Pdt1[4];
    for (int i = 0; i < 4; ++i) { Pdt1[i] = (bf16*)pk; pk += 65536 * 2; }
    __half* P2enc2 = (__half*)pk; pk += 131072 * 4;
    __half* P2enc3 = (__half*)pk; pk += 147456 * 4;
    __half* P2e1w1 = (__half*)pk; pk += 36864 * 4;
    __half* P2e1w2 = (__half*)pk; pk += 4096 * 4;
    __half* P2e2w1 = (__half*)pk; pk += 36864 * 4;
    __half* P2e2w2 = (__half*)pk; pk += 4096 * 4;
    __half* Pe     = (__half*)pk; pk += 131072 * 2;
    __half* Pe1    = (__half*)pk; pk += 8192 * 2;        // enc1 packed weights
    __half* Pdt2   = (__half*)pk; pk += 32768 * 2;       // dt2 packed weights (4 parities)

    float* outY = (float*)d_out;
    float* outF = outY + 3145728;
    float* outQ = outF + 8388608;

    const TapSet t3 = conv_taps(3, 3, 1);
    const TapSet t4 = conv_taps(4, 4, 1);
    const TapSet t1 = conv_taps(1, 1, 0);
    TapSet tdt[4];
    for (int p = 0; p < 4; ++p) tdt[p] = convt_taps(p >> 1, p & 1);

    enorm_k<<<2, 256, 0, stream>>>(emb, EN);
    pack_emb_k<<<256, 256, 0, stream>>>(emb, Pe);
    pack_we1_k<<<16, 256, 0, stream>>>(enc_w1, Pe1);
    pack_wdt2_k<<<64, 256, 0, stream>>>(dt2_w, Pdt2);

    // ---- weight packing (BN=128 for all Co=128 layers) ----
    pack_w_k<<<(147456 + 255) / 256, 256, 0, stream>>>(dec_w, Pdec, 128, 128, 128, t3, 147456);
    pack_w_k<<<(36864 + 255) / 256, 256, 0, stream>>>(drb1_w1, Pd1w1, 128, 32, 32, t3, 36864);
    pack_w_k<<<(4096 + 255) / 256, 256, 0, stream>>>(drb1_w2, Pd1w2, 32, 128, 128, t1, 4096);
    pack_w_k<<<(36864 + 255) / 256, 256, 0, stream>>>(drb2_w1, Pd2w1, 128, 32, 32, t3, 36864);
    pack_w_k<<<(4096 + 255) / 256, 256, 0, stream>>>(drb2_w2, Pd2w2, 32, 128, 128, t1, 4096);
    for (int p = 0; p < 4; ++p)
        pack_w_k<<<(65536 + 255) / 256, 256, 0, stream>>>(dt1_w, Pdt1[p], 128, 64, 64, tdt[p], 65536);
    pack_w2_k<<<(131072 + 255) / 256, 256, 0, stream>>>(enc_w2, P2enc2, 64, 128, 128, t4, 131072);
    pack_w2_k<<<(147456 + 255) / 256, 256, 0, stream>>>(enc_w3, P2enc3, 128, 128, 128, t3, 147456);
    pack_w2_k<<<(36864 + 255) / 256, 256, 0, stream>>>(erb1_w1, P2e1w1, 128, 32, 32, t3, 36864);
    pack_w2_k<<<(4096 + 255) / 256, 256, 0, stream>>>(erb1_w2, P2e1w2, 32, 128, 128, t1, 4096);
    pack_w2_k<<<(36864 + 255) / 256, 256, 0, stream>>>(erb2_w1, P2e2w1, 128, 32, 32, t3, 36864);
    pack_w2_k<<<(4096 + 255) / 256, 256, 0, stream>>>(erb2_w2, P2e2w2, 32, 128, 128, t1, 4096);

    // ---- encoder (fp16-split MFMA) ----
    pad_x_k<<<4096, 256, 0, stream>>>(x, Xh, Xl);
    enc1_mfma_k<<<4096, 256, 0, stream>>>(Xh, Xl, Pe1, enc_b1, H1, L1);
    conv_mfma2_k<128><<<dim3(1024, 1), 256, 0, stream>>>(H1, L1, P2enc2, enc_b2,
        nullptr, H2, L2, nullptr, nullptr, 128, 128, 64, 128, 2, t4, 16, F_OUTRELU);
    conv_mfma2_k<128><<<dim3(1024, 1), 256, 0, stream>>>(H2, L2, P2enc3, enc_b3,
        nullptr, H3, L3, nullptr, nullptr, 64, 64, 128, 128, 1, t3, 9, 0);
    conv_mfma2_k<32><<<dim3(1024, 1), 256, 0, stream>>>(H3, L3, P2e1w1, nullptr,
        nullptr, Ht, Lt, nullptr, nullptr, 64, 64, 128, 32, 1, t3, 9, F_INRELU);
    conv_mfma2_k<128><<<dim3(1024, 1), 256, 0, stream>>>(Ht, Lt, P2e1w2, nullptr,
        nullptr, H4, L4, H3, L3, 64, 64, 32, 128, 1, t1, 1, F_INRELU | F_RES);
    conv_mfma2_k<32><<<dim3(1024, 1), 256, 0, stream>>>(H4, L4, P2e2w1, nullptr,
        nullptr, Ht, Lt, nullptr, nullptr, 64, 64, 128, 32, 1, t3, 9, F_INRELU);
    conv_mfma2_k<128><<<dim3(1024, 1), 256, 0, stream>>>(Ht, Lt, P2e2w2, nullptr,
        outF, Fh, Fl, H4, L4, 64, 64, 32, 128, 1, t1, 1, F_INRELU | F_RES | F_OUTRELU);

    // ---- VQ ----
    vq_mfma_k<<<1024, 256, 0, stream>>>(Fh, Fl, Pe, EN, emb, outQ, Qb);

    // ---- decoder (bf16 MFMA) ----
    conv_mfma_k<128><<<dim3(1024, 1), 256, 0, stream>>>(Qb, Pdec, dec_b, Y0, Db, nullptr,
        128, 128, 64, 64, 1, 0, 0, t3, 9, 0);
    conv_mfma_k<32><<<dim3(1024, 1), 256, 0, stream>>>(Db, Pd1w1, nullptr, nullptr, Tb, nullptr,
        128, 32, 64, 64, 1, 0, 0, t3, 9, F_INRELU);
    conv_mfma_k<128><<<dim3(1024, 1), 256, 0, stream>>>(Tb, Pd1w2, nullptr, Y1, Y1b, Y0,
        32, 128, 64, 64, 1, 0, 0, t1, 1, F_INRELU | F_RES);
    conv_mfma_k<32><<<dim3(1024, 1), 256, 0, stream>>>(Y1b, Pd2w1, nullptr, nullptr, Tb, nullptr,
        128, 32, 64, 64, 1, 0, 0, t3, 9, F_INRELU);
    conv_mfma_k<128><<<dim3(1024, 1), 256, 0, stream>>>(Tb, Pd2w2, nullptr, nullptr, Y2b, Y1,
        32, 128, 64, 64, 1, 0, 0, t1, 1, F_INRELU | F_RES | F_OUTRELU);
    for (int p = 0; p < 4; ++p)
        conv_mfma_k<64><<<dim3(1024, 1), 256, 0, stream>>>(Y2b, Pdt1[p], dt1_b, A1, nullptr, nullptr,
            128, 64, 128, 128, 2, p >> 1, p & 1, tdt[p], 4, F_OUTRELU);

    // ---- dt2 (fp16-split MFMA, LDS A-staging only, B in registers) ----
    dt2_mfma_k<<<16384, 256, 0, stream>>>(A1, Pdt2, dt2_b, outY);
}

// Round 12
// 832.135 us; speedup vs baseline: 1.0353x; 1.0353x over previous
//
#include <hip/hip_runtime.h>
#include <hip/hip_bf16.h>
#include <hip/hip_fp16.h>

using bf16 = __hip_bfloat16;
using frag_ab = __attribute__((ext_vector_type(8))) short;
using f16x8  = __attribute__((ext_vector_type(8))) _Float16;
using hf16x2 = __attribute__((ext_vector_type(2))) __fp16;   // cvt_pkrtz return type
using frag_cd = __attribute__((ext_vector_type(4))) float;

enum { F_INRELU = 1, F_OUTRELU = 2, F_RES = 4 };

struct TapSet { int dy[16]; int dx[16]; int wi[16]; };

__device__ __forceinline__ unsigned int relu_pk(unsigned int v) {
    unsigned int m = ((v & 0x80008000u) >> 15) * 0xFFFFu;
    return v & ~m;
}
__device__ __forceinline__ unsigned int mask_by(unsigned int v, unsigned int h) {
    unsigned int m = ((h & 0x80008000u) >> 15) * 0xFFFFu;
    return v & ~m;
}
// XCD-chunked swizzle: consecutive logical tiles land on the SAME XCD's L2
// (default dispatch round-robins blockIdx across 8 XCDs). Requires n % 8 == 0.
__device__ __forceinline__ int xcd_swz(int bx, int n) {
    return (bx & 7) * (n >> 3) + (bx >> 3);
}

// ---------------- weight pre-pack: bf16 (decoder) ----------------
__global__ void pack_w_k(const float* __restrict__ w, bf16* __restrict__ dst,
                         int Ci, int Co, int BN, TapSet taps, int total)
{
    int idx = blockIdx.x * 256 + threadIdx.x;
    if (idx >= total) return;
    int j  = idx & 7;
    int r1 = idx >> 3;
    int nl = r1 % BN;
    int r2 = r1 / BN;
    int q  = r2 & 3;
    int cb = r2 >> 2;
    int nblocks = Co / BN;
    int c  = cb / nblocks;
    int nb = cb - c * nblocks;
    int cpt = Ci >> 5;
    int tap = c / cpt;
    int ci  = (c - tap * cpt) * 32 + q * 8 + j;
    int n   = nb * BN + nl;
    dst[idx] = __float2bfloat16(w[(size_t)(taps.wi[tap] * Ci + ci) * Co + n]);
}

// ---------------- weight pre-pack: fp16 hi/lo split (encoder) ----------------
__global__ void pack_w2_k(const float* __restrict__ w, __half* __restrict__ dst,
                          int Ci, int Co, int BN, TapSet taps, int total)
{
    int idx = blockIdx.x * 256 + threadIdx.x;
    if (idx >= total) return;
    int j  = idx & 7;
    int r1 = idx >> 3;
    int nl = r1 % BN;
    int r2 = r1 / BN;
    int q  = r2 & 3;
    int cb = r2 >> 2;
    int nblocks = Co / BN;
    int c  = cb / nblocks;
    int nb = cb - c * nblocks;
    int cpt = Ci >> 5;
    int tap = c / cpt;
    int ci  = (c - tap * cpt) * 32 + q * 8 + j;
    int n   = nb * BN + nl;
    float v = w[(size_t)(taps.wi[tap] * Ci + ci) * Co + n];
    __half h = __float2half(v);
    __half l = __float2half((v - __half2float(h)) * 2048.0f);
    size_t base = (size_t)cb * (BN * 64) + (q * BN + nl) * 8 + j;
    dst[base] = h;
    dst[base + BN * 32] = l;
}

// ---------------- dt2 weight pack: (4,4,64,3) -> per-parity K=256, N=16 (pad), hi/lo ----
__global__ void pack_wdt2_k(const float* __restrict__ w, __half* __restrict__ dst)
{
    int idx = blockIdx.x * 256 + threadIdx.x;   // 16384
    if (idx >= 16384) return;
    int parity = idx >> 12;
    int r0 = idx & 4095;
    int j  = r0 & 7;
    int r1 = r0 >> 3;
    int nl = r1 & 15;
    int r2 = r1 >> 4;
    int q  = r2 & 3;
    int cb = r2 >> 2;                 // 0..7
    int tap = cb >> 1;
    int cc  = cb & 1;
    int ci  = cc * 32 + q * 8 + j;
    int n   = nl;
    int py = parity >> 1, px = parity & 1;
    int ty = tap >> 1, tx = tap & 1;
    int wi = (py + 2 * ty) * 4 + (px + 2 * tx);
    float v = (n < 3) ? w[(size_t)(wi * 64 + ci) * 3 + n] : 0.f;
    __half h = __float2half(v);
    __half l = __float2half((v - __half2float(h)) * 2048.0f);
    size_t base = (size_t)parity * 8192 + cb * 1024 + (q * 16 + nl) * 8 + j;
    dst[base] = h;
    dst[base + 512] = l;
}

// ---------------- enc1 weight pack: (4,4,3,64) -> K=64 (4th ch zero), hi/lo ----------------
__global__ void pack_we1_k(const float* __restrict__ w, __half* __restrict__ dst)
{
    int idx = blockIdx.x * 256 + threadIdx.x;   // 2*4*64*8 = 4096
    if (idx >= 4096) return;
    int j  = idx & 7;
    int r1 = idx >> 3;
    int nl = r1 & 63;
    int r2 = r1 >> 6;
    int q  = r2 & 3;
    int c  = r2 >> 2;                 // chunk 0/1
    int k  = c * 32 + q * 8 + j;
    int tap = k >> 2, ci = k & 3;
    float v = (ci < 3) ? w[(size_t)(tap * 3 + ci) * 64 + nl] : 0.f;
    __half h = __float2half(v);
    __half l = __float2half((v - __half2float(h)) * 2048.0f);
    size_t base = (size_t)c * 4096 + (q * 64 + nl) * 8 + j;
    dst[base] = h;
    dst[base + 2048] = l;
}

// ---------------- x pad: (16,256,256,3) fp32 -> (.,4) fp16 hi/lo ----------------
__global__ __launch_bounds__(256) void pad_x_k(
    const float* __restrict__ x, __half* __restrict__ xh, __half* __restrict__ xl)
{
    int pix = blockIdx.x * 256 + threadIdx.x;   // 1048576
    const float* ip = x + (size_t)pix * 3;
    float v0 = ip[0], v1 = ip[1], v2 = ip[2];
    unsigned short hb[4], lb[4];
    float vv[4] = {v0, v1, v2, 0.f};
#pragma unroll
    for (int i = 0; i < 4; ++i) {
        __half h = __float2half(vv[i]);
        hb[i] = __half_as_ushort(h);
        lb[i] = __half_as_ushort(__float2half((vv[i] - __half2float(h)) * 2048.0f));
    }
    uint2 hv = make_uint2((unsigned)hb[0] | ((unsigned)hb[1] << 16),
                          (unsigned)hb[2] | ((unsigned)hb[3] << 16));
    uint2 lv = make_uint2((unsigned)lb[0] | ((unsigned)lb[1] << 16),
                          (unsigned)lb[2] | ((unsigned)lb[3] << 16));
    *(uint2*)(xh + (size_t)pix * 4) = hv;
    *(uint2*)(xl + (size_t)pix * 4) = lv;
}

// ---------------- enc1: 4x4 s2, 4ch padded, fp16-split MFMA ----------------
__global__ __launch_bounds__(256) void enc1_mfma_k(
    const __half* __restrict__ xh, const __half* __restrict__ xl,
    const __half* __restrict__ wp, const float* __restrict__ bias,
    __half* __restrict__ oh, __half* __restrict__ ol)
{
    __shared__ __align__(16) short Ash[64 * 32];
    __shared__ __align__(16) short Asl[64 * 32];
    __shared__ __align__(16) short Bsh[64 * 32];
    __shared__ __align__(16) short Bsl[64 * 32];

    const int tid = threadIdx.x;
    const int m0 = xcd_swz(blockIdx.x, 4096) * 64;

    const int am = tid >> 2;
    const int aq = tid & 3;
    const int gm  = m0 + am;
    const int nn_ = gm >> 14;            // 128*128 pixels/image
    const int rr_ = gm & 16383;
    const int iy0 = (rr_ >> 7) * 2 - 1;
    const int ix0 = (rr_ & 127) * 2 - 1;

    const int lane = tid & 63;
    const int wv4 = tid >> 6;
    const int wm = (wv4 & 1) * 32;
    const int wn = (wv4 >> 1) * 32;
    const int lm = lane & 15, lq = lane >> 4;

    frag_cd accA[2][2], accB[2][2];
#pragma unroll
    for (int i = 0; i < 2; ++i)
#pragma unroll
        for (int j = 0; j < 2; ++j)
#pragma unroll
            for (int r = 0; r < 4; ++r) { accA[i][j][r] = 0.f; accB[i][j][r] = 0.f; }

#pragma unroll
    for (int c = 0; c < 2; ++c) {
        const int tap = c * 8 + aq * 2;
        const int ky = tap >> 2, kx = tap & 3;
        const int iy = iy0 + ky;
        const int ix = ix0 + kx;
        uint2 h0 = make_uint2(0u, 0u), h1 = h0, l0 = h0, l1 = h0;
        if (iy >= 0 && iy < 256) {
            const size_t rowb = (size_t)(nn_ * 256 + iy) * 256;
            if (ix >= 0 && ix < 256) {
                h0 = *(const uint2*)(xh + (rowb + ix) * 4);
                l0 = *(const uint2*)(xl + (rowb + ix) * 4);
            }
            if (ix + 1 >= 0 && ix + 1 < 256) {
                h1 = *(const uint2*)(xh + (rowb + ix + 1) * 4);
                l1 = *(const uint2*)(xl + (rowb + ix + 1) * 4);
            }
        }
        __syncthreads();
        *(uint4*)&Ash[(aq * 64 + am) * 8] = make_uint4(h0.x, h0.y, h1.x, h1.y);
        *(uint4*)&Asl[(aq * 64 + am) * 8] = make_uint4(l0.x, l0.y, l1.x, l1.y);
        {
            const __half* wc = wp + (size_t)c * 4096;
            *(uint4*)&Bsh[tid * 8] = *(const uint4*)(wc + tid * 8);
            *(uint4*)&Bsl[tid * 8] = *(const uint4*)(wc + 2048 + tid * 8);
        }
        __syncthreads();

        f16x8 afh[2], afl[2], bfh[2], bfl[2];
#pragma unroll
        for (int i = 0; i < 2; ++i) {
            afh[i] = *(const f16x8*)&Ash[(lq * 64 + wm + i * 16 + lm) * 8];
            afl[i] = *(const f16x8*)&Asl[(lq * 64 + wm + i * 16 + lm) * 8];
        }
#pragma unroll
        for (int j = 0; j < 2; ++j) {
            bfh[j] = *(const f16x8*)&Bsh[(lq * 64 + wn + j * 16 + lm) * 8];
            bfl[j] = *(const f16x8*)&Bsl[(lq * 64 + wn + j * 16 + lm) * 8];
        }
#pragma unroll
        for (int i = 0; i < 2; ++i)
#pragma unroll
            for (int j = 0; j < 2; ++j) {
                accA[i][j] = __builtin_amdgcn_mfma_f32_16x16x32_f16(afh[i], bfh[j], accA[i][j], 0, 0, 0);
                accB[i][j] = __builtin_amdgcn_mfma_f32_16x16x32_f16(afh[i], bfl[j], accB[i][j], 0, 0, 0);
                accB[i][j] = __builtin_amdgcn_mfma_f32_16x16x32_f16(afl[i], bfh[j], accB[i][j], 0, 0, 0);
            }
    }

    const float s = 1.0f / 2048.0f;
#pragma unroll
    for (int j = 0; j < 2; ++j) {
        const int n_g = wn + j * 16 + lm;
        const float bv = bias[n_g];
#pragma unroll
        for (int i = 0; i < 2; ++i) {
#pragma unroll
            for (int r = 0; r < 4; ++r) {
                const int m_g = m0 + wm + i * 16 + lq * 4 + r;
                const size_t ob = (size_t)m_g * 64 + n_g;
                float v = accA[i][j][r] + accB[i][j][r] * s + bv;
                v = fmaxf(v, 0.f);
                __half h = __float2half(v);
                oh[ob] = h;
                ol[ob] = __float2half((v - __half2float(h)) * 2048.0f);
            }
        }
    }
}

// ---------------- fp16-split MFMA implicit-GEMM conv (encoder) ----------------
// BN=128: one block covers ALL output channels -> A staged/fetched once (was 2x
// via gridDim.y=2) and 24 MFMA per barrier-pair (was 12).  Wave tile 32x64.
template<int BN>
__global__ __launch_bounds__(256) void conv_mfma2_k(
    const __half* __restrict__ ah, const __half* __restrict__ al,
    const __half* __restrict__ wp, const float* __restrict__ bias,
    float* __restrict__ out, __half* __restrict__ oh, __half* __restrict__ ol,
    const __half* __restrict__ rh, const __half* __restrict__ rl,
    int IH, int IW, int Ci, int Co, int sy_in,
    TapSet taps, int ntaps, int flags)
{
    __shared__ __align__(16) short Ash[64 * 32];
    __shared__ __align__(16) short Asl[64 * 32];
    __shared__ __align__(16) short Bsh[BN * 32];
    __shared__ __align__(16) short Bsl[BN * 32];

    const int tid = threadIdx.x;
    const int m0 = xcd_swz(blockIdx.x, gridDim.x) * 64;
    const int n0 = blockIdx.y * BN;

    const int am = tid >> 2;
    const int aq = tid & 3;
    const int gm  = m0 + am;
    const int nn_ = gm >> 12;
    const int rr_ = gm & 4095;
    const int oy_ = (rr_ >> 6) * sy_in;
    const int ox_ = (rr_ & 63) * sy_in;

    const int lane = tid & 63;
    const int wv4 = tid >> 6;
    constexpr int MT = (BN >= 64) ? 2 : 1;
    constexpr int NT = (BN == 128) ? 4 : 2;
    const int wm = (BN >= 64) ? (wv4 & 1) * 32 : wv4 * 16;
    const int wn = (BN == 128) ? (wv4 >> 1) * 64 : ((BN == 64) ? (wv4 >> 1) * 32 : 0);
    const int lm = lane & 15, lq = lane >> 4;
    constexpr int NLOAD = BN * 32 / 8;

    frag_cd accA[MT][NT], accB[MT][NT];
#pragma unroll
    for (int i = 0; i < MT; ++i)
#pragma unroll
        for (int j = 0; j < NT; ++j)
#pragma unroll
            for (int r = 0; r < 4; ++r) { accA[i][j][r] = 0.f; accB[i][j][r] = 0.f; }

    const int cpt = Ci >> 5;
    const int nch = ntaps * cpt;
    const bool inrelu = (flags & F_INRELU) != 0;

    int tap = 0, cc = 0, ci0 = 0;
    for (int c = 0; c < nch; ++c) {
        const int iy = oy_ + taps.dy[tap];
        const int ix = ox_ + taps.dx[tap];
        uint4 avh = make_uint4(0u, 0u, 0u, 0u);
        uint4 avl = make_uint4(0u, 0u, 0u, 0u);
        if (iy >= 0 && iy < IH && ix >= 0 && ix < IW) {
            const size_t off = (size_t)((nn_ * IH + iy) * IW + ix) * Ci + ci0 + aq * 8;
            avh = *(const uint4*)(ah + off);
            avl = *(const uint4*)(al + off);
        }
        if (inrelu) {
            avl.x = mask_by(avl.x, avh.x); avl.y = mask_by(avl.y, avh.y);
            avl.z = mask_by(avl.z, avh.z); avl.w = mask_by(avl.w, avh.w);
            avh.x = relu_pk(avh.x); avh.y = relu_pk(avh.y);
            avh.z = relu_pk(avh.z); avh.w = relu_pk(avh.w);
        }
        uint4 bvh0, bvl0, bvh1, bvl1;
        {
            const __half* wc = wp + (size_t)(c * gridDim.y + blockIdx.y) * (BN * 64);
            if constexpr (BN == 128) {
                bvh0 = *(const uint4*)(wc + tid * 8);
                bvh1 = *(const uint4*)(wc + (256 + tid) * 8);
                bvl0 = *(const uint4*)(wc + BN * 32 + tid * 8);
                bvl1 = *(const uint4*)(wc + BN * 32 + (256 + tid) * 8);
            } else if (tid < NLOAD) {
                bvh0 = *(const uint4*)(wc + tid * 8);
                bvl0 = *(const uint4*)(wc + BN * 32 + tid * 8);
            }
        }

        __syncthreads();
        *(uint4*)&Ash[(aq * 64 + am) * 8] = avh;
        *(uint4*)&Asl[(aq * 64 + am) * 8] = avl;
        if constexpr (BN == 128) {
            *(uint4*)&Bsh[tid * 8] = bvh0;
            *(uint4*)&Bsh[(256 + tid) * 8] = bvh1;
            *(uint4*)&Bsl[tid * 8] = bvl0;
            *(uint4*)&Bsl[(256 + tid) * 8] = bvl1;
        } else if (tid < NLOAD) {
            *(uint4*)&Bsh[tid * 8] = bvh0;
            *(uint4*)&Bsl[tid * 8] = bvl0;
        }
        __syncthreads();

        f16x8 afh[MT], afl[MT], bfh[NT], bfl[NT];
#pragma unroll
        for (int i = 0; i < MT; ++i) {
            afh[i] = *(const f16x8*)&Ash[(lq * 64 + wm + i * 16 + lm) * 8];
            afl[i] = *(const f16x8*)&Asl[(lq * 64 + wm + i * 16 + lm) * 8];
        }
#pragma unroll
        for (int j = 0; j < NT; ++j) {
            bfh[j] = *(const f16x8*)&Bsh[(lq * BN + wn + j * 16 + lm) * 8];
            bfl[j] = *(const f16x8*)&Bsl[(lq * BN + wn + j * 16 + lm) * 8];
        }
#pragma unroll
        for (int i = 0; i < MT; ++i)
#pragma unroll
            for (int j = 0; j < NT; ++j) {
                accA[i][j] = __builtin_amdgcn_mfma_f32_16x16x32_f16(afh[i], bfh[j], accA[i][j], 0, 0, 0);
                accB[i][j] = __builtin_amdgcn_mfma_f32_16x16x32_f16(afh[i], bfl[j], accB[i][j], 0, 0, 0);
                accB[i][j] = __builtin_amdgcn_mfma_f32_16x16x32_f16(afl[i], bfh[j], accB[i][j], 0, 0, 0);
            }

        ci0 += 32;
        if (++cc == cpt) { cc = 0; ci0 = 0; ++tap; }
    }

    const float s = 1.0f / 2048.0f;
#pragma unroll
    for (int j = 0; j < NT; ++j) {
        const int n_g = n0 + wn + j * 16 + lm;
        const float bv = bias ? bias[n_g] : 0.f;
#pragma unroll
        for (int i = 0; i < MT; ++i) {
#pragma unroll
            for (int r = 0; r < 4; ++r) {
                const int m_g = m0 + wm + i * 16 + lq * 4 + r;
                const size_t ob = (size_t)m_g * Co + n_g;
                float v = accA[i][j][r] + accB[i][j][r] * s + bv;
                if (flags & F_RES)
                    v += __half2float(rh[ob]) + __half2float(rl[ob]) * s;
                if (flags & F_OUTRELU) v = fmaxf(v, 0.f);
                if (out) out[ob] = v;
                if (oh) {
                    __half h = __float2half(v);
                    oh[ob] = h;
                    ol[ob] = __float2half((v - __half2float(h)) * 2048.0f);
                }
            }
        }
    }
}

// ---------------- bf16 MFMA implicit-GEMM conv (decoder) ----------------
template<int BN>
__global__ __launch_bounds__(256) void conv_mfma_k(
    const bf16* __restrict__ a, const bf16* __restrict__ wp,
    const float* __restrict__ bias,
    float* __restrict__ out, bf16* __restrict__ out_bf,
    const float* __restrict__ res,
    int Ci, int Co, int OHf, int OWf, int sy_out, int py, int px,
    TapSet taps, int ntaps, int flags)
{
    __shared__ __align__(16) short As[64 * 32];
    __shared__ __align__(16) short Bs[BN * 32];

    const int tid = threadIdx.x;
    const int m0 = xcd_swz(blockIdx.x, gridDim.x) * 64;
    const int n0 = blockIdx.y * BN;

    const int am = tid >> 2;
    const int aq = tid & 3;
    const int gm  = m0 + am;
    const int nn_ = gm >> 12;
    const int rr_ = gm & 4095;
    const int oy_ = rr_ >> 6;
    const int ox_ = rr_ & 63;

    const int lane = tid & 63;
    const int wv4 = tid >> 6;
    constexpr int MT = (BN >= 64) ? 2 : 1;
    constexpr int NT = (BN == 128) ? 4 : 2;
    const int wm = (BN >= 64) ? (wv4 & 1) * 32 : wv4 * 16;
    const int wn = (BN == 128) ? (wv4 >> 1) * 64 : ((BN == 64) ? (wv4 >> 1) * 32 : 0);
    const int lm = lane & 15, lq = lane >> 4;
    constexpr int NLOAD = BN * 32 / 8;

    frag_cd acc[MT][NT];
#pragma unroll
    for (int i = 0; i < MT; ++i)
#pragma unroll
        for (int j = 0; j < NT; ++j)
#pragma unroll
            for (int r = 0; r < 4; ++r) acc[i][j][r] = 0.f;

    const int cpt = Ci >> 5;
    const int nch = ntaps * cpt;
    const bool inrelu = (flags & F_INRELU) != 0;

    int tap = 0, cc = 0, ci0 = 0;
    for (int c = 0; c < nch; ++c) {
        const int iy = oy_ + taps.dy[tap];
        const int ix = ox_ + taps.dx[tap];
        uint4 av = make_uint4(0u, 0u, 0u, 0u);
        if (iy >= 0 && iy < 64 && ix >= 0 && ix < 64)
            av = *(const uint4*)(a + (size_t)((nn_ * 64 + iy) * 64 + ix) * Ci + ci0 + aq * 8);
        if (inrelu) {
            av.x = relu_pk(av.x); av.y = relu_pk(av.y);
            av.z = relu_pk(av.z); av.w = relu_pk(av.w);
        }
        uint4 bv0, bv1;
        {
            const bf16* wc = wp + ((size_t)c * gridDim.y + blockIdx.y) * (BN * 32);
            if constexpr (BN == 128) {
                bv0 = *(const uint4*)(wc + tid * 8);
                bv1 = *(const uint4*)(wc + (256 + tid) * 8);
            } else if (tid < NLOAD) {
                bv0 = *(const uint4*)(wc + tid * 8);
            }
        }

        __syncthreads();
        *(uint4*)&As[(aq * 64 + am) * 8] = av;
        if constexpr (BN == 128) {
            *(uint4*)&Bs[tid * 8] = bv0;
            *(uint4*)&Bs[(256 + tid) * 8] = bv1;
        } else if (tid < NLOAD) {
            *(uint4*)&Bs[tid * 8] = bv0;
        }
        __syncthreads();

        frag_ab af[MT], bfr[NT];
#pragma unroll
        for (int i = 0; i < MT; ++i)
            af[i] = *(const frag_ab*)&As[(lq * 64 + wm + i * 16 + lm) * 8];
#pragma unroll
        for (int j = 0; j < NT; ++j)
            bfr[j] = *(const frag_ab*)&Bs[(lq * BN + wn + j * 16 + lm) * 8];
#pragma unroll
        for (int i = 0; i < MT; ++i)
#pragma unroll
            for (int j = 0; j < NT; ++j)
                acc[i][j] = __builtin_amdgcn_mfma_f32_16x16x32_bf16(af[i], bfr[j], acc[i][j], 0, 0, 0);

        ci0 += 32;
        if (++cc == cpt) { cc = 0; ci0 = 0; ++tap; }
    }

#pragma unroll
    for (int j = 0; j < NT; ++j) {
        const int n_g = n0 + wn + j * 16 + lm;
        const float bv = bias ? bias[n_g] : 0.f;
#pragma unroll
        for (int i = 0; i < MT; ++i) {
#pragma unroll
            for (int r = 0; r < 4; ++r) {
                const int m_g = m0 + wm + i * 16 + lq * 4 + r;
                const int nn2 = m_g >> 12;
                const int rr2 = m_g & 4095;
                const int oy = (rr2 >> 6) * sy_out + py;
                const int ox = (rr2 & 63) * sy_out + px;
                const size_t ob = ((size_t)(nn2 * OHf + oy) * OWf + ox) * Co + n_g;
                float v = acc[i][j][r] + bv;
                if (flags & F_RES)     v += res[ob];
                if (flags & F_OUTRELU) v = fmaxf(v, 0.f);
                if (out)    out[ob]    = v;
                if (out_bf) out_bf[ob] = __float2bfloat16(v);
            }
        }
    }
}

// ---------------- dt2: convT 4x4 s2, 64->3 via fp16-split MFMA -------------------
// Round-11 lesson: B-in-regs fails (compiler re-materializes loads in-loop,
// occupancy 80->42%, dur 92->114).  B returns to LDS (r10 structure, 92us).
// Round-12 change: MERGE CHUNK PAIRS.  Chunks 2t and 2t+1 are the two 32-ch
// halves of the SAME pixel (same iy,ix; ci0 = 0/32).  Stage the full pixel
// per phase: 4 phases instead of 8 -> barriers and staging-latency exposures
// HALVED, 6 MFMA per phase.  Total LDS wave-ops unchanged (intrinsic b128
// cost; r11 proved conflicts are all A-path and layout-intrinsic).
// LDS 20KB -> 8 blocks/CU, occupancy stays high.
__global__ __launch_bounds__(256) void dt2_mfma_k(
    const float* __restrict__ in,      // A1: (16,128,128,64) fp32, relu'd
    const __half* __restrict__ wp,     // packed per-parity weights (4 x 8192 halves)
    const float* __restrict__ bias,    // 3
    float* __restrict__ out)           // (16,256,256,3)
{
    __shared__ __align__(16) short Ash[2][64 * 32];
    __shared__ __align__(16) short Asl[2][64 * 32];
    __shared__ __align__(16) short Bsh[2][16 * 32];
    __shared__ __align__(16) short Bsl[2][16 * 32];

    const int tid = threadIdx.x;
    const int bx  = xcd_swz(blockIdx.x, 16384);   // parity quads stay on one XCD
    const int par = bx & 3;
    const int m0  = (bx >> 2) * 64;
    const int py = par >> 1, px = par & 1;

    const int am = tid >> 2;
    const int aq = tid & 3;
    const int gm  = m0 + am;
    const int nn_ = gm >> 14;            // image
    const int rr_ = gm & 16383;
    const int r_  = rr_ >> 7;            // 0..127
    const int c_  = rr_ & 127;

    const int lane = tid & 63;
    const int wv4 = tid >> 6;
    const int wm = wv4 * 16;
    const int lm = lane & 15, lq = lane >> 4;

    frag_cd accA, accB;
#pragma unroll
    for (int r = 0; r < 4; ++r) { accA[r] = 0.f; accB[r] = 0.f; }

    const __half* wpar = wp + (size_t)par * 8192;

    for (int t = 0; t < 4; ++t) {
        const int iy = r_ + py + (t >> 1) - 1;
        const int ix = c_ + px + (t & 1) - 1;
        uint4 hi0 = make_uint4(0u, 0u, 0u, 0u), lo0 = hi0, hi1 = hi0, lo1 = hi0;
        if ((unsigned)iy < 128u && (unsigned)ix < 128u) {
            const float* ip = in + (size_t)((nn_ * 128 + iy) * 128 + ix) * 64 + aq * 8;
#pragma unroll
            for (int h = 0; h < 2; ++h) {
                const float4 v0 = *(const float4*)(ip + h * 32);
                const float4 v1 = *(const float4*)(ip + h * 32 + 4);
                const float vv[8] = {v0.x, v0.y, v0.z, v0.w, v1.x, v1.y, v1.z, v1.w};
                union { hf16x2 p[4]; uint4 u; } uh, ul;
#pragma unroll
                for (int i = 0; i < 4; ++i) {
                    hf16x2 hh = __builtin_amdgcn_cvt_pkrtz(vv[2 * i], vv[2 * i + 1]);
                    uh.p[i] = hh;
                    ul.p[i] = __builtin_amdgcn_cvt_pkrtz(
                        (vv[2 * i]     - (float)hh[0]) * 2048.f,
                        (vv[2 * i + 1] - (float)hh[1]) * 2048.f);
                }
                if (h == 0) { hi0 = uh.u; lo0 = ul.u; }
                else        { hi1 = uh.u; lo1 = ul.u; }
            }
        }
        uint4 bvh, bvl;
        if (tid < 128) {
            const __half* wc = wpar + (size_t)(2 * t + (tid >> 6)) * 1024 + (tid & 63) * 8;
            bvh = *(const uint4*)wc;
            bvl = *(const uint4*)(wc + 512);
        }

        __syncthreads();
        *(uint4*)&Ash[0][(aq * 64 + am) * 8] = hi0;
        *(uint4*)&Asl[0][(aq * 64 + am) * 8] = lo0;
        *(uint4*)&Ash[1][(aq * 64 + am) * 8] = hi1;
        *(uint4*)&Asl[1][(aq * 64 + am) * 8] = lo1;
        if (tid < 128) {
            *(uint4*)&Bsh[tid >> 6][(tid & 63) * 8] = bvh;
            *(uint4*)&Bsl[tid >> 6][(tid & 63) * 8] = bvl;
        }
        __syncthreads();

#pragma unroll
        for (int h = 0; h < 2; ++h) {
            const f16x8 afh = *(const f16x8*)&Ash[h][(lq * 64 + wm + lm) * 8];
            const f16x8 afl = *(const f16x8*)&Asl[h][(lq * 64 + wm + lm) * 8];
            const f16x8 bfh = *(const f16x8*)&Bsh[h][(lq * 16 + lm) * 8];
            const f16x8 bfl = *(const f16x8*)&Bsl[h][(lq * 16 + lm) * 8];
            accA = __builtin_amdgcn_mfma_f32_16x16x32_f16(afh, bfh, accA, 0, 0, 0);
            accB = __builtin_amdgcn_mfma_f32_16x16x32_f16(afh, bfl, accB, 0, 0, 0);
            accB = __builtin_amdgcn_mfma_f32_16x16x32_f16(afl, bfh, accB, 0, 0, 0);
        }
    }

    const float s = 1.0f / 2048.0f;
    if (lm < 3) {
        const float bv = bias[lm];
#pragma unroll
        for (int r = 0; r < 4; ++r) {
            const int m_g = m0 + wm + lq * 4 + r;
            const int nn2 = m_g >> 14;
            const int rr2 = m_g & 16383;
            const int oy = (rr2 >> 7) * 2 + py;
            const int ox = (rr2 & 127) * 2 + px;
            out[((size_t)(nn2 * 256 + oy) * 256 + ox) * 3 + lm] = accA[r] + accB[r] * s + bv;
        }
    }
}

// ---------------- VQ ----------------
__global__ void enorm_k(const float* __restrict__ emb, float* __restrict__ en) {
    int k = blockIdx.x * 256 + threadIdx.x;
    if (k >= 512) return;
    const float4* e = (const float4*)(emb + k * 128);
    float s = 0.f;
    for (int i = 0; i < 32; ++i) {
        float4 v = e[i];
        s += v.x * v.x + v.y * v.y + v.z * v.z + v.w * v.w;
    }
    en[k] = s;
}

__global__ void pack_emb_k(const float* __restrict__ emb, __half* __restrict__ dst)
{
    int idx = blockIdx.x * 256 + threadIdx.x;   // 65536
    int k = idx & 127;
    int n = idx >> 7;
    float v = emb[idx];
    __half h = __float2half(v);
    __half l = __float2half((v - __half2float(h)) * 2048.0f);
    int nb = n >> 6, nl = n & 63;
    int ch = k >> 5, q = (k >> 3) & 3, j = k & 7;
    size_t base = (size_t)(nb * 4 + ch) * 4096 + (q * 64 + nl) * 8 + j;
    dst[base] = h;
    dst[base + 2048] = l;
}

__global__ __launch_bounds__(256) void vq_mfma_k(
    const __half* __restrict__ fh, const __half* __restrict__ fl,
    const __half* __restrict__ pe, const float* __restrict__ en,
    const float* __restrict__ emb, float* __restrict__ q, bf16* __restrict__ qb)
{
    __shared__ __align__(16) short Ash[64 * 128];
    __shared__ __align__(16) short Asl[64 * 128];
    __shared__ int sel[64];

    const int tid  = threadIdx.x;
    const int pos0 = blockIdx.x * 64;

    {
        const int am = tid >> 2;
        const int aq = tid & 3;
#pragma unroll
        for (int ch = 0; ch < 4; ++ch) {
            const size_t off = (size_t)(pos0 + am) * 128 + ch * 32 + aq * 8;
            uint4 vh = *(const uint4*)(fh + off);
            uint4 vl = *(const uint4*)(fl + off);
            *(uint4*)&Ash[((ch * 4 + aq) * 64 + am) * 8] = vh;
            *(uint4*)&Asl[((ch * 4 + aq) * 64 + am) * 8] = vl;
        }
    }
    __syncthreads();

    const int lane = tid & 63;
    const int w    = tid >> 6;
    const int lm = lane & 15, lq = lane >> 4;
    const int mbase = w * 16;
    const float s = 1.0f / 2048.0f;

    float best[4] = {3.4e38f, 3.4e38f, 3.4e38f, 3.4e38f};
    int   bidx[4] = {0, 0, 0, 0};

    f16x8 ah[4], alv[4];
#pragma unroll
    for (int ch = 0; ch < 4; ++ch) {
        ah[ch]  = *(const f16x8*)&Ash[((ch * 4 + lq) * 64 + mbase + lm) * 8];
        alv[ch] = *(const f16x8*)&Asl[((ch * 4 + lq) * 64 + mbase + lm) * 8];
    }

    for (int nb = 0; nb < 8; ++nb) {
        frag_cd accA[4], accB[4];
#pragma unroll
        for (int j = 0; j < 4; ++j)
#pragma unroll
            for (int r = 0; r < 4; ++r) { accA[j][r] = 0.f; accB[j][r] = 0.f; }

#pragma unroll
        for (int ch = 0; ch < 4; ++ch) {
            const __half* base = pe + (size_t)(nb * 4 + ch) * 4096;
            f16x8 bh[4], bl[4];
#pragma unroll
            for (int j = 0; j < 4; ++j) {
                const int o = (lq * 64 + j * 16 + lm) * 8;
                bh[j] = *(const f16x8*)(base + o);
                bl[j] = *(const f16x8*)(base + 2048 + o);
            }
#pragma unroll
            for (int j = 0; j < 4; ++j) {
                accA[j] = __builtin_amdgcn_mfma_f32_16x16x32_f16(ah[ch], bh[j], accA[j], 0, 0, 0);
                accB[j] = __builtin_amdgcn_mfma_f32_16x16x32_f16(ah[ch], bl[j], accB[j], 0, 0, 0);
                accB[j] = __builtin_amdgcn_mfma_f32_16x16x32_f16(alv[ch], bh[j], accB[j], 0, 0, 0);
            }
        }

#pragma unroll
        for (int j = 0; j < 4; ++j) {
            const int code = nb * 64 + j * 16 + lm;
            const float ec = en[code];
#pragma unroll
            for (int r = 0; r < 4; ++r) {
                float dot = accA[j][r] + accB[j][r] * s;
                float d = fmaf(dot, -2.f, ec);
                if (d < best[r]) { best[r] = d; bidx[r] = code; }
            }
        }
    }

#pragma unroll
    for (int r = 0; r < 4; ++r) {
        float d = best[r]; int ix = bidx[r];
#pragma unroll
        for (int m = 1; m < 16; m <<= 1) {
            float d2 = __shfl_xor(d, m);
            int   x2 = __shfl_xor(ix, m);
            if (d2 < d || (d2 == d && x2 < ix)) { d = d2; ix = x2; }
        }
        if (lm == 0) sel[mbase + lq * 4 + r] = ix;
    }
    __syncthreads();

#pragma unroll
    for (int jj = 0; jj < 32; ++jj) {
        int id = jj * 256 + tid;
        int p = id >> 7, k = id & 127;
        float v = emb[(size_t)sel[p] * 128 + k];
        q[(size_t)(pos0 + p) * 128 + k]  = v;
        qb[(size_t)(pos0 + p) * 128 + k] = __float2bfloat16(v);
    }
}

// ---------------- host ----------------
static TapSet conv_taps(int KH, int KW, int pad) {
    TapSet t{};
    for (int ky = 0; ky < KH; ++ky)
        for (int kx = 0; kx < KW; ++kx) {
            int i = ky * KW + kx;
            t.dy[i] = ky - pad; t.dx[i] = kx - pad; t.wi[i] = i;
        }
    return t;
}

static TapSet convt_taps(int py, int px) {
    TapSet t{};
    for (int ty = 0; ty < 2; ++ty)
        for (int tx = 0; tx < 2; ++tx) {
            int i = ty * 2 + tx;
            t.dy[i] = py + ty - 1;
            t.dx[i] = px + tx - 1;
            t.wi[i] = (py + 2 * ty) * 4 + (px + 2 * tx);
        }
    return t;
}

extern "C" void kernel_launch(void* const* d_in, const int* in_sizes, int n_in,
                              void* d_out, int out_size, void* d_ws, size_t ws_size,
                              hipStream_t stream)
{
    const float* x       = (const float*)d_in[0];
    const float* emb     = (const float*)d_in[1];
    const float* enc_w1  = (const float*)d_in[2];
    const float* enc_b1  = (const float*)d_in[3];
    const float* enc_w2  = (const float*)d_in[4];
    const float* enc_b2  = (const float*)d_in[5];
    const float* enc_w3  = (const float*)d_in[6];
    const float* enc_b3  = (const float*)d_in[7];
    const float* erb1_w1 = (const float*)d_in[8];
    const float* erb1_w2 = (const float*)d_in[9];
    const float* erb2_w1 = (const float*)d_in[10];
    const float* erb2_w2 = (const float*)d_in[11];
    const float* dec_w   = (const float*)d_in[12];
    const float* dec_b   = (const float*)d_in[13];
    const float* drb1_w1 = (const float*)d_in[14];
    const float* drb1_w2 = (const float*)d_in[15];
    const float* drb2_w1 = (const float*)d_in[16];
    const float* drb2_w2 = (const float*)d_in[17];
    const float* dt1_w   = (const float*)d_in[18];
    const float* dt1_b   = (const float*)d_in[19];
    const float* dt2_w   = (const float*)d_in[20];
    const float* dt2_b   = (const float*)d_in[21];

    char* wsb = (char*)d_ws;
    __half* H1 = (__half*)wsb;                           // 33.55 MB
    __half* L1 = (__half*)(wsb + (size_t)33554432);      // 33.55 MB
    __half* H2 = (__half*)(wsb + (size_t)67108864);      // 16.78 MB
    __half* L2 = (__half*)(wsb + (size_t)83886080);      // 16.78 MB
    // x padded planes alias the (not-yet-written) H2/L2 region
    __half* Xh = (__half*)(wsb + (size_t)67108864);      // 8.39 MB
    __half* Xl = (__half*)(wsb + (size_t)75497472);      // 8.39 MB
    __half* H3 = (__half*)wsb;
    __half* L3 = (__half*)(wsb + (size_t)16777216);
    __half* H4 = (__half*)(wsb + (size_t)33554432);
    __half* L4 = (__half*)(wsb + (size_t)50331648);
    __half* Ht = (__half*)(wsb + (size_t)100663296);     // 4.19 MB
    __half* Lt = (__half*)(wsb + (size_t)104857600);     // 4.19 MB
    float*  EN = (float*)(wsb + (size_t)109051904);      // 2 KB
    __half* Fh = (__half*)wsb;
    __half* Fl = (__half*)(wsb + (size_t)16777216);
    bf16* Qb  = (bf16*)(wsb + (size_t)67108864);
    bf16* Db  = (bf16*)(wsb + (size_t)83886080);
    bf16* Y1b = Qb;
    bf16* Y2b = Db;
    bf16* Tb  = (bf16*)(wsb + (size_t)100663296);
    float* Y0 = (float*)wsb;
    float* Y1 = (float*)(wsb + (size_t)33554432);
    float* A1 = (float*)wsb;
    char* pk = wsb + (size_t)109056000;
    bf16* Pdec  = (bf16*)pk;  pk += 147456 * 2;
    bf16* Pd1w1 = (bf16*)pk;  pk += 36864 * 2;
    bf16* Pd1w2 = (bf16*)pk;  pk += 4096 * 2;
    bf16* Pd2w1 = (bf16*)pk;  pk += 36864 * 2;
    bf16* Pd2w2 = (bf16*)pk;  pk += 4096 * 2;
    bf16* Pdt1[4];
    for (int i = 0; i < 4; ++i) { Pdt1[i] = (bf16*)pk; pk += 65536 * 2; }
    __half* P2enc2 = (__half*)pk; pk += 131072 * 4;
    __half* P2enc3 = (__half*)pk; pk += 147456 * 4;
    __half* P2e1w1 = (__half*)pk; pk += 36864 * 4;
    __half* P2e1w2 = (__half*)pk; pk += 4096 * 4;
    __half* P2e2w1 = (__half*)pk; pk += 36864 * 4;
    __half* P2e2w2 = (__half*)pk; pk += 4096 * 4;
    __half* Pe     = (__half*)pk; pk += 131072 * 2;
    __half* Pe1    = (__half*)pk; pk += 8192 * 2;        // enc1 packed weights
    __half* Pdt2   = (__half*)pk; pk += 32768 * 2;       // dt2 packed weights (4 parities)

    float* outY = (float*)d_out;
    float* outF = outY + 3145728;
    float* outQ = outF + 8388608;

    const TapSet t3 = conv_taps(3, 3, 1);
    const TapSet t4 = conv_taps(4, 4, 1);
    const TapSet t1 = conv_taps(1, 1, 0);
    TapSet tdt[4];
    for (int p = 0; p < 4; ++p) tdt[p] = convt_taps(p >> 1, p & 1);

    enorm_k<<<2, 256, 0, stream>>>(emb, EN);
    pack_emb_k<<<256, 256, 0, stream>>>(emb, Pe);
    pack_we1_k<<<16, 256, 0, stream>>>(enc_w1, Pe1);
    pack_wdt2_k<<<64, 256, 0, stream>>>(dt2_w, Pdt2);

    // ---- weight packing (BN=128 for all Co=128 layers) ----
    pack_w_k<<<(147456 + 255) / 256, 256, 0, stream>>>(dec_w, Pdec, 128, 128, 128, t3, 147456);
    pack_w_k<<<(36864 + 255) / 256, 256, 0, stream>>>(drb1_w1, Pd1w1, 128, 32, 32, t3, 36864);
    pack_w_k<<<(4096 + 255) / 256, 256, 0, stream>>>(drb1_w2, Pd1w2, 32, 128, 128, t1, 4096);
    pack_w_k<<<(36864 + 255) / 256, 256, 0, stream>>>(drb2_w1, Pd2w1, 128, 32, 32, t3, 36864);
    pack_w_k<<<(4096 + 255) / 256, 256, 0, stream>>>(drb2_w2, Pd2w2, 32, 128, 128, t1, 4096);
    for (int p = 0; p < 4; ++p)
        pack_w_k<<<(65536 + 255) / 256, 256, 0, stream>>>(dt1_w, Pdt1[p], 128, 64, 64, tdt[p], 65536);
    pack_w2_k<<<(131072 + 255) / 256, 256, 0, stream>>>(enc_w2, P2enc2, 64, 128, 128, t4, 131072);
    pack_w2_k<<<(147456 + 255) / 256, 256, 0, stream>>>(enc_w3, P2enc3, 128, 128, 128, t3, 147456);
    pack_w2_k<<<(36864 + 255) / 256, 256, 0, stream>>>(erb1_w1, P2e1w1, 128, 32, 32, t3, 36864);
    pack_w2_k<<<(4096 + 255) / 256, 256, 0, stream>>>(erb1_w2, P2e1w2, 32, 128, 128, t1, 4096);
    pack_w2_k<<<(36864 + 255) / 256, 256, 0, stream>>>(erb2_w1, P2e2w1, 128, 32, 32, t3, 36864);
    pack_w2_k<<<(4096 + 255) / 256, 256, 0, stream>>>(erb2_w2, P2e2w2, 32, 128, 128, t1, 4096);

    // ---- encoder (fp16-split MFMA) ----
    pad_x_k<<<4096, 256, 0, stream>>>(x, Xh, Xl);
    enc1_mfma_k<<<4096, 256, 0, stream>>>(Xh, Xl, Pe1, enc_b1, H1, L1);
    conv_mfma2_k<128><<<dim3(1024, 1), 256, 0, stream>>>(H1, L1, P2enc2, enc_b2,
        nullptr, H2, L2, nullptr, nullptr, 128, 128, 64, 128, 2, t4, 16, F_OUTRELU);
    conv_mfma2_k<128><<<dim3(1024, 1), 256, 0, stream>>>(H2, L2, P2enc3, enc_b3,
        nullptr, H3, L3, nullptr, nullptr, 64, 64, 128, 128, 1, t3, 9, 0);
    conv_mfma2_k<32><<<dim3(1024, 1), 256, 0, stream>>>(H3, L3, P2e1w1, nullptr,
        nullptr, Ht, Lt, nullptr, nullptr, 64, 64, 128, 32, 1, t3, 9, F_INRELU);
    conv_mfma2_k<128><<<dim3(1024, 1), 256, 0, stream>>>(Ht, Lt, P2e1w2, nullptr,
        nullptr, H4, L4, H3, L3, 64, 64, 32, 128, 1, t1, 1, F_INRELU | F_RES);
    conv_mfma2_k<32><<<dim3(1024, 1), 256, 0, stream>>>(H4, L4, P2e2w1, nullptr,
        nullptr, Ht, Lt, nullptr, nullptr, 64, 64, 128, 32, 1, t3, 9, F_INRELU);
    conv_mfma2_k<128><<<dim3(1024, 1), 256, 0, stream>>>(Ht, Lt, P2e2w2, nullptr,
        outF, Fh, Fl, H4, L4, 64, 64, 32, 128, 1, t1, 1, F_INRELU | F_RES | F_OUTRELU);

    // ---- VQ ----
    vq_mfma_k<<<1024, 256, 0, stream>>>(Fh, Fl, Pe, EN, emb, outQ, Qb);

    // ---- decoder (bf16 MFMA) ----
    conv_mfma_k<128><<<dim3(1024, 1), 256, 0, stream>>>(Qb, Pdec, dec_b, Y0, Db, nullptr,
        128, 128, 64, 64, 1, 0, 0, t3, 9, 0);
    conv_mfma_k<32><<<dim3(1024, 1), 256, 0, stream>>>(Db, Pd1w1, nullptr, nullptr, Tb, nullptr,
        128, 32, 64, 64, 1, 0, 0, t3, 9, F_INRELU);
    conv_mfma_k<128><<<dim3(1024, 1), 256, 0, stream>>>(Tb, Pd1w2, nullptr, Y1, Y1b, Y0,
        32, 128, 64, 64, 1, 0, 0, t1, 1, F_INRELU | F_RES);
    conv_mfma_k<32><<<dim3(1024, 1), 256, 0, stream>>>(Y1b, Pd2w1, nullptr, nullptr, Tb, nullptr,
        128, 32, 64, 64, 1, 0, 0, t3, 9, F_INRELU);
    conv_mfma_k<128><<<dim3(1024, 1), 256, 0, stream>>>(Tb, Pd2w2, nullptr, nullptr, Y2b, Y1,
        32, 128, 64, 64, 1, 0, 0, t1, 1, F_INRELU | F_RES | F_OUTRELU);
    for (int p = 0; p < 4; ++p)
        conv_mfma_k<64><<<dim3(1024, 1), 256, 0, stream>>>(Y2b, Pdt1[p], dt1_b, A1, nullptr, nullptr,
            128, 64, 128, 128, 2, p >> 1, p & 1, tdt[p], 4, F_OUTRELU);

    // ---- dt2 (fp16-split MFMA, merged chunk-pairs: 4 phases, 6 MFMA each) ----
    dt2_mfma_k<<<16384, 256, 0, stream>>>(A1, Pdt2, dt2_b, outY);
}

// Round 13
// 802.857 us; speedup vs baseline: 1.0731x; 1.0365x over previous
//
#include <hip/hip_runtime.h>
#include <hip/hip_bf16.h>
#include <hip/hip_fp16.h>

using bf16 = __hip_bfloat16;
using frag_ab = __attribute__((ext_vector_type(8))) short;
using f16x8  = __attribute__((ext_vector_type(8))) _Float16;
using hf16x2 = __attribute__((ext_vector_type(2))) __fp16;   // cvt_pkrtz return type
using frag_cd = __attribute__((ext_vector_type(4))) float;

enum { F_INRELU = 1, F_OUTRELU = 2, F_RES = 4 };

struct TapSet { int dy[16]; int dx[16]; int wi[16]; };

__device__ __forceinline__ unsigned int relu_pk(unsigned int v) {
    unsigned int m = ((v & 0x80008000u) >> 15) * 0xFFFFu;
    return v & ~m;
}
__device__ __forceinline__ unsigned int mask_by(unsigned int v, unsigned int h) {
    unsigned int m = ((h & 0x80008000u) >> 15) * 0xFFFFu;
    return v & ~m;
}
// XCD-chunked swizzle: consecutive logical tiles land on the SAME XCD's L2
// (default dispatch round-robins blockIdx across 8 XCDs). Requires n % 8 == 0.
__device__ __forceinline__ int xcd_swz(int bx, int n) {
    return (bx & 7) * (n >> 3) + (bx >> 3);
}

// ---------------- weight pre-pack: bf16 (decoder) ----------------
__global__ void pack_w_k(const float* __restrict__ w, bf16* __restrict__ dst,
                         int Ci, int Co, int BN, TapSet taps, int total)
{
    int idx = blockIdx.x * 256 + threadIdx.x;
    if (idx >= total) return;
    int j  = idx & 7;
    int r1 = idx >> 3;
    int nl = r1 % BN;
    int r2 = r1 / BN;
    int q  = r2 & 3;
    int cb = r2 >> 2;
    int nblocks = Co / BN;
    int c  = cb / nblocks;
    int nb = cb - c * nblocks;
    int cpt = Ci >> 5;
    int tap = c / cpt;
    int ci  = (c - tap * cpt) * 32 + q * 8 + j;
    int n   = nb * BN + nl;
    dst[idx] = __float2bfloat16(w[(size_t)(taps.wi[tap] * Ci + ci) * Co + n]);
}

// ---------------- weight pre-pack: fp16 hi/lo split (encoder) ----------------
__global__ void pack_w2_k(const float* __restrict__ w, __half* __restrict__ dst,
                          int Ci, int Co, int BN, TapSet taps, int total)
{
    int idx = blockIdx.x * 256 + threadIdx.x;
    if (idx >= total) return;
    int j  = idx & 7;
    int r1 = idx >> 3;
    int nl = r1 % BN;
    int r2 = r1 / BN;
    int q  = r2 & 3;
    int cb = r2 >> 2;
    int nblocks = Co / BN;
    int c  = cb / nblocks;
    int nb = cb - c * nblocks;
    int cpt = Ci >> 5;
    int tap = c / cpt;
    int ci  = (c - tap * cpt) * 32 + q * 8 + j;
    int n   = nb * BN + nl;
    float v = w[(size_t)(taps.wi[tap] * Ci + ci) * Co + n];
    __half h = __float2half(v);
    __half l = __float2half((v - __half2float(h)) * 2048.0f);
    size_t base = (size_t)cb * (BN * 64) + (q * BN + nl) * 8 + j;
    dst[base] = h;
    dst[base + BN * 32] = l;
}

// ---------------- dt2 weight pack: (4,4,64,3) -> per-parity K=256, N=16 (pad), hi/lo ----
__global__ void pack_wdt2_k(const float* __restrict__ w, __half* __restrict__ dst)
{
    int idx = blockIdx.x * 256 + threadIdx.x;   // 16384
    if (idx >= 16384) return;
    int parity = idx >> 12;
    int r0 = idx & 4095;
    int j  = r0 & 7;
    int r1 = r0 >> 3;
    int nl = r1 & 15;
    int r2 = r1 >> 4;
    int q  = r2 & 3;
    int cb = r2 >> 2;                 // 0..7
    int tap = cb >> 1;
    int cc  = cb & 1;
    int ci  = cc * 32 + q * 8 + j;
    int n   = nl;
    int py = parity >> 1, px = parity & 1;
    int ty = tap >> 1, tx = tap & 1;
    int wi = (py + 2 * ty) * 4 + (px + 2 * tx);
    float v = (n < 3) ? w[(size_t)(wi * 64 + ci) * 3 + n] : 0.f;
    __half h = __float2half(v);
    __half l = __float2half((v - __half2float(h)) * 2048.0f);
    size_t base = (size_t)parity * 8192 + cb * 1024 + (q * 16 + nl) * 8 + j;
    dst[base] = h;
    dst[base + 512] = l;
}

// ---------------- enc1 weight pack: (4,4,3,64) -> K=64 (4th ch zero), hi/lo ----------------
__global__ void pack_we1_k(const float* __restrict__ w, __half* __restrict__ dst)
{
    int idx = blockIdx.x * 256 + threadIdx.x;   // 2*4*64*8 = 4096
    if (idx >= 4096) return;
    int j  = idx & 7;
    int r1 = idx >> 3;
    int nl = r1 & 63;
    int r2 = r1 >> 6;
    int q  = r2 & 3;
    int c  = r2 >> 2;                 // chunk 0/1
    int k  = c * 32 + q * 8 + j;
    int tap = k >> 2, ci = k & 3;
    float v = (ci < 3) ? w[(size_t)(tap * 3 + ci) * 64 + nl] : 0.f;
    __half h = __float2half(v);
    __half l = __float2half((v - __half2float(h)) * 2048.0f);
    size_t base = (size_t)c * 4096 + (q * 64 + nl) * 8 + j;
    dst[base] = h;
    dst[base + 2048] = l;
}

// ---------------- x pad: (16,256,256,3) fp32 -> (.,4) fp16 hi/lo ----------------
__global__ __launch_bounds__(256) void pad_x_k(
    const float* __restrict__ x, __half* __restrict__ xh, __half* __restrict__ xl)
{
    int pix = blockIdx.x * 256 + threadIdx.x;   // 1048576
    const float* ip = x + (size_t)pix * 3;
    float v0 = ip[0], v1 = ip[1], v2 = ip[2];
    unsigned short hb[4], lb[4];
    float vv[4] = {v0, v1, v2, 0.f};
#pragma unroll
    for (int i = 0; i < 4; ++i) {
        __half h = __float2half(vv[i]);
        hb[i] = __half_as_ushort(h);
        lb[i] = __half_as_ushort(__float2half((vv[i] - __half2float(h)) * 2048.0f));
    }
    uint2 hv = make_uint2((unsigned)hb[0] | ((unsigned)hb[1] << 16),
                          (unsigned)hb[2] | ((unsigned)hb[3] << 16));
    uint2 lv = make_uint2((unsigned)lb[0] | ((unsigned)lb[1] << 16),
                          (unsigned)lb[2] | ((unsigned)lb[3] << 16));
    *(uint2*)(xh + (size_t)pix * 4) = hv;
    *(uint2*)(xl + (size_t)pix * 4) = lv;
}

// ---------------- enc1: 4x4 s2, 4ch padded, fp16-split MFMA ----------------
__global__ __launch_bounds__(256) void enc1_mfma_k(
    const __half* __restrict__ xh, const __half* __restrict__ xl,
    const __half* __restrict__ wp, const float* __restrict__ bias,
    __half* __restrict__ oh, __half* __restrict__ ol)
{
    __shared__ __align__(16) short Ash[64 * 32];
    __shared__ __align__(16) short Asl[64 * 32];
    __shared__ __align__(16) short Bsh[64 * 32];
    __shared__ __align__(16) short Bsl[64 * 32];

    const int tid = threadIdx.x;
    const int m0 = xcd_swz(blockIdx.x, 4096) * 64;

    const int am = tid >> 2;
    const int aq = tid & 3;
    const int gm  = m0 + am;
    const int nn_ = gm >> 14;            // 128*128 pixels/image
    const int rr_ = gm & 16383;
    const int iy0 = (rr_ >> 7) * 2 - 1;
    const int ix0 = (rr_ & 127) * 2 - 1;

    const int lane = tid & 63;
    const int wv4 = tid >> 6;
    const int wm = (wv4 & 1) * 32;
    const int wn = (wv4 >> 1) * 32;
    const int lm = lane & 15, lq = lane >> 4;

    frag_cd accA[2][2], accB[2][2];
#pragma unroll
    for (int i = 0; i < 2; ++i)
#pragma unroll
        for (int j = 0; j < 2; ++j)
#pragma unroll
            for (int r = 0; r < 4; ++r) { accA[i][j][r] = 0.f; accB[i][j][r] = 0.f; }

#pragma unroll
    for (int c = 0; c < 2; ++c) {
        const int tap = c * 8 + aq * 2;
        const int ky = tap >> 2, kx = tap & 3;
        const int iy = iy0 + ky;
        const int ix = ix0 + kx;
        uint2 h0 = make_uint2(0u, 0u), h1 = h0, l0 = h0, l1 = h0;
        if (iy >= 0 && iy < 256) {
            const size_t rowb = (size_t)(nn_ * 256 + iy) * 256;
            if (ix >= 0 && ix < 256) {
                h0 = *(const uint2*)(xh + (rowb + ix) * 4);
                l0 = *(const uint2*)(xl + (rowb + ix) * 4);
            }
            if (ix + 1 >= 0 && ix + 1 < 256) {
                h1 = *(const uint2*)(xh + (rowb + ix + 1) * 4);
                l1 = *(const uint2*)(xl + (rowb + ix + 1) * 4);
            }
        }
        __syncthreads();
        *(uint4*)&Ash[(aq * 64 + am) * 8] = make_uint4(h0.x, h0.y, h1.x, h1.y);
        *(uint4*)&Asl[(aq * 64 + am) * 8] = make_uint4(l0.x, l0.y, l1.x, l1.y);
        {
            const __half* wc = wp + (size_t)c * 4096;
            *(uint4*)&Bsh[tid * 8] = *(const uint4*)(wc + tid * 8);
            *(uint4*)&Bsl[tid * 8] = *(const uint4*)(wc + 2048 + tid * 8);
        }
        __syncthreads();

        f16x8 afh[2], afl[2], bfh[2], bfl[2];
#pragma unroll
        for (int i = 0; i < 2; ++i) {
            afh[i] = *(const f16x8*)&Ash[(lq * 64 + wm + i * 16 + lm) * 8];
            afl[i] = *(const f16x8*)&Asl[(lq * 64 + wm + i * 16 + lm) * 8];
        }
#pragma unroll
        for (int j = 0; j < 2; ++j) {
            bfh[j] = *(const f16x8*)&Bsh[(lq * 64 + wn + j * 16 + lm) * 8];
            bfl[j] = *(const f16x8*)&Bsl[(lq * 64 + wn + j * 16 + lm) * 8];
        }
#pragma unroll
        for (int i = 0; i < 2; ++i)
#pragma unroll
            for (int j = 0; j < 2; ++j) {
                accA[i][j] = __builtin_amdgcn_mfma_f32_16x16x32_f16(afh[i], bfh[j], accA[i][j], 0, 0, 0);
                accB[i][j] = __builtin_amdgcn_mfma_f32_16x16x32_f16(afh[i], bfl[j], accB[i][j], 0, 0, 0);
                accB[i][j] = __builtin_amdgcn_mfma_f32_16x16x32_f16(afl[i], bfh[j], accB[i][j], 0, 0, 0);
            }
    }

    const float s = 1.0f / 2048.0f;
#pragma unroll
    for (int j = 0; j < 2; ++j) {
        const int n_g = wn + j * 16 + lm;
        const float bv = bias[n_g];
#pragma unroll
        for (int i = 0; i < 2; ++i) {
#pragma unroll
            for (int r = 0; r < 4; ++r) {
                const int m_g = m0 + wm + i * 16 + lq * 4 + r;
                const size_t ob = (size_t)m_g * 64 + n_g;
                float v = accA[i][j][r] + accB[i][j][r] * s + bv;
                v = fmaxf(v, 0.f);
                __half h = __float2half(v);
                oh[ob] = h;
                ol[ob] = __float2half((v - __half2float(h)) * 2048.0f);
            }
        }
    }
}

// ---------------- fp16-split MFMA implicit-GEMM conv (encoder) ----------------
// BN=128: one block covers ALL output channels -> A staged/fetched once (was 2x
// via gridDim.y=2) and 24 MFMA per barrier-pair (was 12).  Wave tile 32x64.
template<int BN>
__global__ __launch_bounds__(256) void conv_mfma2_k(
    const __half* __restrict__ ah, const __half* __restrict__ al,
    const __half* __restrict__ wp, const float* __restrict__ bias,
    float* __restrict__ out, __half* __restrict__ oh, __half* __restrict__ ol,
    const __half* __restrict__ rh, const __half* __restrict__ rl,
    int IH, int IW, int Ci, int Co, int sy_in,
    TapSet taps, int ntaps, int flags)
{
    __shared__ __align__(16) short Ash[64 * 32];
    __shared__ __align__(16) short Asl[64 * 32];
    __shared__ __align__(16) short Bsh[BN * 32];
    __shared__ __align__(16) short Bsl[BN * 32];

    const int tid = threadIdx.x;
    const int m0 = xcd_swz(blockIdx.x, gridDim.x) * 64;
    const int n0 = blockIdx.y * BN;

    const int am = tid >> 2;
    const int aq = tid & 3;
    const int gm  = m0 + am;
    const int nn_ = gm >> 12;
    const int rr_ = gm & 4095;
    const int oy_ = (rr_ >> 6) * sy_in;
    const int ox_ = (rr_ & 63) * sy_in;

    const int lane = tid & 63;
    const int wv4 = tid >> 6;
    constexpr int MT = (BN >= 64) ? 2 : 1;
    constexpr int NT = (BN == 128) ? 4 : 2;
    const int wm = (BN >= 64) ? (wv4 & 1) * 32 : wv4 * 16;
    const int wn = (BN == 128) ? (wv4 >> 1) * 64 : ((BN == 64) ? (wv4 >> 1) * 32 : 0);
    const int lm = lane & 15, lq = lane >> 4;
    constexpr int NLOAD = BN * 32 / 8;

    frag_cd accA[MT][NT], accB[MT][NT];
#pragma unroll
    for (int i = 0; i < MT; ++i)
#pragma unroll
        for (int j = 0; j < NT; ++j)
#pragma unroll
            for (int r = 0; r < 4; ++r) { accA[i][j][r] = 0.f; accB[i][j][r] = 0.f; }

    const int cpt = Ci >> 5;
    const int nch = ntaps * cpt;
    const bool inrelu = (flags & F_INRELU) != 0;

    int tap = 0, cc = 0, ci0 = 0;
    for (int c = 0; c < nch; ++c) {
        const int iy = oy_ + taps.dy[tap];
        const int ix = ox_ + taps.dx[tap];
        uint4 avh = make_uint4(0u, 0u, 0u, 0u);
        uint4 avl = make_uint4(0u, 0u, 0u, 0u);
        if (iy >= 0 && iy < IH && ix >= 0 && ix < IW) {
            const size_t off = (size_t)((nn_ * IH + iy) * IW + ix) * Ci + ci0 + aq * 8;
            avh = *(const uint4*)(ah + off);
            avl = *(const uint4*)(al + off);
        }
        if (inrelu) {
            avl.x = mask_by(avl.x, avh.x); avl.y = mask_by(avl.y, avh.y);
            avl.z = mask_by(avl.z, avh.z); avl.w = mask_by(avl.w, avh.w);
            avh.x = relu_pk(avh.x); avh.y = relu_pk(avh.y);
            avh.z = relu_pk(avh.z); avh.w = relu_pk(avh.w);
        }
        uint4 bvh0, bvl0, bvh1, bvl1;
        {
            const __half* wc = wp + (size_t)(c * gridDim.y + blockIdx.y) * (BN * 64);
            if constexpr (BN == 128) {
                bvh0 = *(const uint4*)(wc + tid * 8);
                bvh1 = *(const uint4*)(wc + (256 + tid) * 8);
                bvl0 = *(const uint4*)(wc + BN * 32 + tid * 8);
                bvl1 = *(const uint4*)(wc + BN * 32 + (256 + tid) * 8);
            } else if (tid < NLOAD) {
                bvh0 = *(const uint4*)(wc + tid * 8);
                bvl0 = *(const uint4*)(wc + BN * 32 + tid * 8);
            }
        }

        __syncthreads();
        *(uint4*)&Ash[(aq * 64 + am) * 8] = avh;
        *(uint4*)&Asl[(aq * 64 + am) * 8] = avl;
        if constexpr (BN == 128) {
            *(uint4*)&Bsh[tid * 8] = bvh0;
            *(uint4*)&Bsh[(256 + tid) * 8] = bvh1;
            *(uint4*)&Bsl[tid * 8] = bvl0;
            *(uint4*)&Bsl[(256 + tid) * 8] = bvl1;
        } else if (tid < NLOAD) {
            *(uint4*)&Bsh[tid * 8] = bvh0;
            *(uint4*)&Bsl[tid * 8] = bvl0;
        }
        __syncthreads();

        f16x8 afh[MT], afl[MT], bfh[NT], bfl[NT];
#pragma unroll
        for (int i = 0; i < MT; ++i) {
            afh[i] = *(const f16x8*)&Ash[(lq * 64 + wm + i * 16 + lm) * 8];
            afl[i] = *(const f16x8*)&Asl[(lq * 64 + wm + i * 16 + lm) * 8];
        }
#pragma unroll
        for (int j = 0; j < NT; ++j) {
            bfh[j] = *(const f16x8*)&Bsh[(lq * BN + wn + j * 16 + lm) * 8];
            bfl[j] = *(const f16x8*)&Bsl[(lq * BN + wn + j * 16 + lm) * 8];
        }
#pragma unroll
        for (int i = 0; i < MT; ++i)
#pragma unroll
            for (int j = 0; j < NT; ++j) {
                accA[i][j] = __builtin_amdgcn_mfma_f32_16x16x32_f16(afh[i], bfh[j], accA[i][j], 0, 0, 0);
                accB[i][j] = __builtin_amdgcn_mfma_f32_16x16x32_f16(afh[i], bfl[j], accB[i][j], 0, 0, 0);
                accB[i][j] = __builtin_amdgcn_mfma_f32_16x16x32_f16(afl[i], bfh[j], accB[i][j], 0, 0, 0);
            }

        ci0 += 32;
        if (++cc == cpt) { cc = 0; ci0 = 0; ++tap; }
    }

    const float s = 1.0f / 2048.0f;
#pragma unroll
    for (int j = 0; j < NT; ++j) {
        const int n_g = n0 + wn + j * 16 + lm;
        const float bv = bias ? bias[n_g] : 0.f;
#pragma unroll
        for (int i = 0; i < MT; ++i) {
#pragma unroll
            for (int r = 0; r < 4; ++r) {
                const int m_g = m0 + wm + i * 16 + lq * 4 + r;
                const size_t ob = (size_t)m_g * Co + n_g;
                float v = accA[i][j][r] + accB[i][j][r] * s + bv;
                if (flags & F_RES)
                    v += __half2float(rh[ob]) + __half2float(rl[ob]) * s;
                if (flags & F_OUTRELU) v = fmaxf(v, 0.f);
                if (out) out[ob] = v;
                if (oh) {
                    __half h = __float2half(v);
                    oh[ob] = h;
                    ol[ob] = __float2half((v - __half2float(h)) * 2048.0f);
                }
            }
        }
    }
}

// ---------------- bf16 MFMA implicit-GEMM conv (decoder) ----------------
template<int BN>
__global__ __launch_bounds__(256) void conv_mfma_k(
    const bf16* __restrict__ a, const bf16* __restrict__ wp,
    const float* __restrict__ bias,
    float* __restrict__ out, bf16* __restrict__ out_bf,
    const float* __restrict__ res,
    int Ci, int Co, int OHf, int OWf, int sy_out, int py, int px,
    TapSet taps, int ntaps, int flags)
{
    __shared__ __align__(16) short As[64 * 32];
    __shared__ __align__(16) short Bs[BN * 32];

    const int tid = threadIdx.x;
    const int m0 = xcd_swz(blockIdx.x, gridDim.x) * 64;
    const int n0 = blockIdx.y * BN;

    const int am = tid >> 2;
    const int aq = tid & 3;
    const int gm  = m0 + am;
    const int nn_ = gm >> 12;
    const int rr_ = gm & 4095;
    const int oy_ = rr_ >> 6;
    const int ox_ = rr_ & 63;

    const int lane = tid & 63;
    const int wv4 = tid >> 6;
    constexpr int MT = (BN >= 64) ? 2 : 1;
    constexpr int NT = (BN == 128) ? 4 : 2;
    const int wm = (BN >= 64) ? (wv4 & 1) * 32 : wv4 * 16;
    const int wn = (BN == 128) ? (wv4 >> 1) * 64 : ((BN == 64) ? (wv4 >> 1) * 32 : 0);
    const int lm = lane & 15, lq = lane >> 4;
    constexpr int NLOAD = BN * 32 / 8;

    frag_cd acc[MT][NT];
#pragma unroll
    for (int i = 0; i < MT; ++i)
#pragma unroll
        for (int j = 0; j < NT; ++j)
#pragma unroll
            for (int r = 0; r < 4; ++r) acc[i][j][r] = 0.f;

    const int cpt = Ci >> 5;
    const int nch = ntaps * cpt;
    const bool inrelu = (flags & F_INRELU) != 0;

    int tap = 0, cc = 0, ci0 = 0;
    for (int c = 0; c < nch; ++c) {
        const int iy = oy_ + taps.dy[tap];
        const int ix = ox_ + taps.dx[tap];
        uint4 av = make_uint4(0u, 0u, 0u, 0u);
        if (iy >= 0 && iy < 64 && ix >= 0 && ix < 64)
            av = *(const uint4*)(a + (size_t)((nn_ * 64 + iy) * 64 + ix) * Ci + ci0 + aq * 8);
        if (inrelu) {
            av.x = relu_pk(av.x); av.y = relu_pk(av.y);
            av.z = relu_pk(av.z); av.w = relu_pk(av.w);
        }
        uint4 bv0, bv1;
        {
            const bf16* wc = wp + ((size_t)c * gridDim.y + blockIdx.y) * (BN * 32);
            if constexpr (BN == 128) {
                bv0 = *(const uint4*)(wc + tid * 8);
                bv1 = *(const uint4*)(wc + (256 + tid) * 8);
            } else if (tid < NLOAD) {
                bv0 = *(const uint4*)(wc + tid * 8);
            }
        }

        __syncthreads();
        *(uint4*)&As[(aq * 64 + am) * 8] = av;
        if constexpr (BN == 128) {
            *(uint4*)&Bs[tid * 8] = bv0;
            *(uint4*)&Bs[(256 + tid) * 8] = bv1;
        } else if (tid < NLOAD) {
            *(uint4*)&Bs[tid * 8] = bv0;
        }
        __syncthreads();

        frag_ab af[MT], bfr[NT];
#pragma unroll
        for (int i = 0; i < MT; ++i)
            af[i] = *(const frag_ab*)&As[(lq * 64 + wm + i * 16 + lm) * 8];
#pragma unroll
        for (int j = 0; j < NT; ++j)
            bfr[j] = *(const frag_ab*)&Bs[(lq * BN + wn + j * 16 + lm) * 8];
#pragma unroll
        for (int i = 0; i < MT; ++i)
#pragma unroll
            for (int j = 0; j < NT; ++j)
                acc[i][j] = __builtin_amdgcn_mfma_f32_16x16x32_bf16(af[i], bfr[j], acc[i][j], 0, 0, 0);

        ci0 += 32;
        if (++cc == cpt) { cc = 0; ci0 = 0; ++tap; }
    }

#pragma unroll
    for (int j = 0; j < NT; ++j) {
        const int n_g = n0 + wn + j * 16 + lm;
        const float bv = bias ? bias[n_g] : 0.f;
#pragma unroll
        for (int i = 0; i < MT; ++i) {
#pragma unroll
            for (int r = 0; r < 4; ++r) {
                const int m_g = m0 + wm + i * 16 + lq * 4 + r;
                const int nn2 = m_g >> 12;
                const int rr2 = m_g & 4095;
                const int oy = (rr2 >> 6) * sy_out + py;
                const int ox = (rr2 & 63) * sy_out + px;
                const size_t ob = ((size_t)(nn2 * OHf + oy) * OWf + ox) * Co + n_g;
                float v = acc[i][j][r] + bv;
                if (flags & F_RES)     v += res[ob];
                if (flags & F_OUTRELU) v = fmaxf(v, 0.f);
                if (out)    out[ob]    = v;
                if (out_bf) out_bf[ob] = __float2bfloat16(v);
            }
        }
    }
}

// ---------------- dt2: convT 4x4 s2, 64->3 via fp16 MFMA (A-hi only) -------------
// r10-r12 forensics: SQ_LDS_BANK_CONFLICT bit-identical (2.517e7) across B-in-LDS,
// B-in-regs, and phase-merged variants -> the count tracks A traffic only and is
// the INTRINSIC multi-cycle cost of wave64 b128 LDS ops (1KB through 128B/clk).
// Only less A traffic helps.  This round: DROP THE A-side lo term.  dt2 is the
// terminal layer (VQ is upstream); dropping a_lo x b_hi leaves A at fp16-RTZ
// precision -> |dOut| ~ 2-5e-4, far under the stable absmax 0.015625.  B keeps
// hi/lo (weight rounding vs fp32 reference; tiny LDS share).  Effects: A LDS
// writes+reads halved, residual-convert VALU gone, LDS 20K->12K.
__global__ __launch_bounds__(256) void dt2_mfma_k(
    const float* __restrict__ in,      // A1: (16,128,128,64) fp32, relu'd
    const __half* __restrict__ wp,     // packed per-parity weights (4 x 8192 halves)
    const float* __restrict__ bias,    // 3
    float* __restrict__ out)           // (16,256,256,3)
{
    __shared__ __align__(16) short Ash[2][64 * 32];
    __shared__ __align__(16) short Bsh[2][16 * 32];
    __shared__ __align__(16) short Bsl[2][16 * 32];

    const int tid = threadIdx.x;
    const int bx  = xcd_swz(blockIdx.x, 16384);   // parity quads stay on one XCD
    const int par = bx & 3;
    const int m0  = (bx >> 2) * 64;
    const int py = par >> 1, px = par & 1;

    const int am = tid >> 2;
    const int aq = tid & 3;
    const int gm  = m0 + am;
    const int nn_ = gm >> 14;            // image
    const int rr_ = gm & 16383;
    const int r_  = rr_ >> 7;            // 0..127
    const int c_  = rr_ & 127;

    const int lane = tid & 63;
    const int wv4 = tid >> 6;
    const int wm = wv4 * 16;
    const int lm = lane & 15, lq = lane >> 4;

    frag_cd accA, accB;
#pragma unroll
    for (int r = 0; r < 4; ++r) { accA[r] = 0.f; accB[r] = 0.f; }

    const __half* wpar = wp + (size_t)par * 8192;

    for (int t = 0; t < 4; ++t) {
        const int iy = r_ + py + (t >> 1) - 1;
        const int ix = c_ + px + (t & 1) - 1;
        uint4 hi0 = make_uint4(0u, 0u, 0u, 0u), hi1 = hi0;
        if ((unsigned)iy < 128u && (unsigned)ix < 128u) {
            const float* ip = in + (size_t)((nn_ * 128 + iy) * 128 + ix) * 64 + aq * 8;
#pragma unroll
            for (int h = 0; h < 2; ++h) {
                const float4 v0 = *(const float4*)(ip + h * 32);
                const float4 v1 = *(const float4*)(ip + h * 32 + 4);
                union { hf16x2 p[4]; uint4 u; } uh;
                uh.p[0] = __builtin_amdgcn_cvt_pkrtz(v0.x, v0.y);
                uh.p[1] = __builtin_amdgcn_cvt_pkrtz(v0.z, v0.w);
                uh.p[2] = __builtin_amdgcn_cvt_pkrtz(v1.x, v1.y);
                uh.p[3] = __builtin_amdgcn_cvt_pkrtz(v1.z, v1.w);
                if (h == 0) hi0 = uh.u; else hi1 = uh.u;
            }
        }
        uint4 bvh, bvl;
        if (tid < 128) {
            const __half* wc = wpar + (size_t)(2 * t + (tid >> 6)) * 1024 + (tid & 63) * 8;
            bvh = *(const uint4*)wc;
            bvl = *(const uint4*)(wc + 512);
        }

        __syncthreads();
        *(uint4*)&Ash[0][(aq * 64 + am) * 8] = hi0;
        *(uint4*)&Ash[1][(aq * 64 + am) * 8] = hi1;
        if (tid < 128) {
            *(uint4*)&Bsh[tid >> 6][(tid & 63) * 8] = bvh;
            *(uint4*)&Bsl[tid >> 6][(tid & 63) * 8] = bvl;
        }
        __syncthreads();

#pragma unroll
        for (int h = 0; h < 2; ++h) {
            const f16x8 afh = *(const f16x8*)&Ash[h][(lq * 64 + wm + lm) * 8];
            const f16x8 bfh = *(const f16x8*)&Bsh[h][(lq * 16 + lm) * 8];
            const f16x8 bfl = *(const f16x8*)&Bsl[h][(lq * 16 + lm) * 8];
            accA = __builtin_amdgcn_mfma_f32_16x16x32_f16(afh, bfh, accA, 0, 0, 0);
            accB = __builtin_amdgcn_mfma_f32_16x16x32_f16(afh, bfl, accB, 0, 0, 0);
        }
    }

    const float s = 1.0f / 2048.0f;
    if (lm < 3) {
        const float bv = bias[lm];
#pragma unroll
        for (int r = 0; r < 4; ++r) {
            const int m_g = m0 + wm + lq * 4 + r;
            const int nn2 = m_g >> 14;
            const int rr2 = m_g & 16383;
            const int oy = (rr2 >> 7) * 2 + py;
            const int ox = (rr2 & 127) * 2 + px;
            out[((size_t)(nn2 * 256 + oy) * 256 + ox) * 3 + lm] = accA[r] + accB[r] * s + bv;
        }
    }
}

// ---------------- VQ ----------------
__global__ void enorm_k(const float* __restrict__ emb, float* __restrict__ en) {
    int k = blockIdx.x * 256 + threadIdx.x;
    if (k >= 512) return;
    const float4* e = (const float4*)(emb + k * 128);
    float s = 0.f;
    for (int i = 0; i < 32; ++i) {
        float4 v = e[i];
        s += v.x * v.x + v.y * v.y + v.z * v.z + v.w * v.w;
    }
    en[k] = s;
}

__global__ void pack_emb_k(const float* __restrict__ emb, __half* __restrict__ dst)
{
    int idx = blockIdx.x * 256 + threadIdx.x;   // 65536
    int k = idx & 127;
    int n = idx >> 7;
    float v = emb[idx];
    __half h = __float2half(v);
    __half l = __float2half((v - __half2float(h)) * 2048.0f);
    int nb = n >> 6, nl = n & 63;
    int ch = k >> 5, q = (k >> 3) & 3, j = k & 7;
    size_t base = (size_t)(nb * 4 + ch) * 4096 + (q * 64 + nl) * 8 + j;
    dst[base] = h;
    dst[base + 2048] = l;
}

__global__ __launch_bounds__(256) void vq_mfma_k(
    const __half* __restrict__ fh, const __half* __restrict__ fl,
    const __half* __restrict__ pe, const float* __restrict__ en,
    const float* __restrict__ emb, float* __restrict__ q, bf16* __restrict__ qb)
{
    __shared__ __align__(16) short Ash[64 * 128];
    __shared__ __align__(16) short Asl[64 * 128];
    __shared__ int sel[64];

    const int tid  = threadIdx.x;
    const int pos0 = blockIdx.x * 64;

    {
        const int am = tid >> 2;
        const int aq = tid & 3;
#pragma unroll
        for (int ch = 0; ch < 4; ++ch) {
            const size_t off = (size_t)(pos0 + am) * 128 + ch * 32 + aq * 8;
            uint4 vh = *(const uint4*)(fh + off);
            uint4 vl = *(const uint4*)(fl + off);
            *(uint4*)&Ash[((ch * 4 + aq) * 64 + am) * 8] = vh;
            *(uint4*)&Asl[((ch * 4 + aq) * 64 + am) * 8] = vl;
        }
    }
    __syncthreads();

    const int lane = tid & 63;
    const int w    = tid >> 6;
    const int lm = lane & 15, lq = lane >> 4;
    const int mbase = w * 16;
    const float s = 1.0f / 2048.0f;

    float best[4] = {3.4e38f, 3.4e38f, 3.4e38f, 3.4e38f};
    int   bidx[4] = {0, 0, 0, 0};

    f16x8 ah[4], alv[4];
#pragma unroll
    for (int ch = 0; ch < 4; ++ch) {
        ah[ch]  = *(const f16x8*)&Ash[((ch * 4 + lq) * 64 + mbase + lm) * 8];
        alv[ch] = *(const f16x8*)&Asl[((ch * 4 + lq) * 64 + mbase + lm) * 8];
    }

    for (int nb = 0; nb < 8; ++nb) {
        frag_cd accA[4], accB[4];
#pragma unroll
        for (int j = 0; j < 4; ++j)
#pragma unroll
            for (int r = 0; r < 4; ++r) { accA[j][r] = 0.f; accB[j][r] = 0.f; }

#pragma unroll
        for (int ch = 0; ch < 4; ++ch) {
            const __half* base = pe + (size_t)(nb * 4 + ch) * 4096;
            f16x8 bh[4], bl[4];
#pragma unroll
            for (int j = 0; j < 4; ++j) {
                const int o = (lq * 64 + j * 16 + lm) * 8;
                bh[j] = *(const f16x8*)(base + o);
                bl[j] = *(const f16x8*)(base + 2048 + o);
            }
#pragma unroll
            for (int j = 0; j < 4; ++j) {
                accA[j] = __builtin_amdgcn_mfma_f32_16x16x32_f16(ah[ch], bh[j], accA[j], 0, 0, 0);
                accB[j] = __builtin_amdgcn_mfma_f32_16x16x32_f16(ah[ch], bl[j], accB[j], 0, 0, 0);
                accB[j] = __builtin_amdgcn_mfma_f32_16x16x32_f16(alv[ch], bh[j], accB[j], 0, 0, 0);
            }
        }

#pragma unroll
        for (int j = 0; j < 4; ++j) {
            const int code = nb * 64 + j * 16 + lm;
            const float ec = en[code];
#pragma unroll
            for (int r = 0; r < 4; ++r) {
                float dot = accA[j][r] + accB[j][r] * s;
                float d = fmaf(dot, -2.f, ec);
                if (d < best[r]) { best[r] = d; bidx[r] = code; }
            }
        }
    }

#pragma unroll
    for (int r = 0; r < 4; ++r) {
        float d = best[r]; int ix = bidx[r];
#pragma unroll
        for (int m = 1; m < 16; m <<= 1) {
            float d2 = __shfl_xor(d, m);
            int   x2 = __shfl_xor(ix, m);
            if (d2 < d || (d2 == d && x2 < ix)) { d = d2; ix = x2; }
        }
        if (lm == 0) sel[mbase + lq * 4 + r] = ix;
    }
    __syncthreads();

#pragma unroll
    for (int jj = 0; jj < 32; ++jj) {
        int id = jj * 256 + tid;
        int p = id >> 7, k = id & 127;
        float v = emb[(size_t)sel[p] * 128 + k];
        q[(size_t)(pos0 + p) * 128 + k]  = v;
        qb[(size_t)(pos0 + p) * 128 + k] = __float2bfloat16(v);
    }
}

// ---------------- host ----------------
static TapSet conv_taps(int KH, int KW, int pad) {
    TapSet t{};
    for (int ky = 0; ky < KH; ++ky)
        for (int kx = 0; kx < KW; ++kx) {
            int i = ky * KW + kx;
            t.dy[i] = ky - pad; t.dx[i] = kx - pad; t.wi[i] = i;
        }
    return t;
}

static TapSet convt_taps(int py, int px) {
    TapSet t{};
    for (int ty = 0; ty < 2; ++ty)
        for (int tx = 0; tx < 2; ++tx) {
            int i = ty * 2 + tx;
            t.dy[i] = py + ty - 1;
            t.dx[i] = px + tx - 1;
            t.wi[i] = (py + 2 * ty) * 4 + (px + 2 * tx);
        }
    return t;
}

extern "C" void kernel_launch(void* const* d_in, const int* in_sizes, int n_in,
                              void* d_out, int out_size, void* d_ws, size_t ws_size,
                              hipStream_t stream)
{
    const float* x       = (const float*)d_in[0];
    const float* emb     = (const float*)d_in[1];
    const float* enc_w1  = (const float*)d_in[2];
    const float* enc_b1  = (const float*)d_in[3];
    const float* enc_w2  = (const float*)d_in[4];
    const float* enc_b2  = (const float*)d_in[5];
    const float* enc_w3  = (const float*)d_in[6];
    const float* enc_b3  = (const float*)d_in[7];
    const float* erb1_w1 = (const float*)d_in[8];
    const float* erb1_w2 = (const float*)d_in[9];
    const float* erb2_w1 = (const float*)d_in[10];
    const float* erb2_w2 = (const float*)d_in[11];
    const float* dec_w   = (const float*)d_in[12];
    const float* dec_b   = (const float*)d_in[13];
    const float* drb1_w1 = (const float*)d_in[14];
    const float* drb1_w2 = (const float*)d_in[15];
    const float* drb2_w1 = (const float*)d_in[16];
    const float* drb2_w2 = (const float*)d_in[17];
    const float* dt1_w   = (const float*)d_in[18];
    const float* dt1_b   = (const float*)d_in[19];
    const float* dt2_w   = (const float*)d_in[20];
    const float* dt2_b   = (const float*)d_in[21];

    char* wsb = (char*)d_ws;
    __half* H1 = (__half*)wsb;                           // 33.55 MB
    __half* L1 = (__half*)(wsb + (size_t)33554432);      // 33.55 MB
    __half* H2 = (__half*)(wsb + (size_t)67108864);      // 16.78 MB
    __half* L2 = (__half*)(wsb + (size_t)83886080);      // 16.78 MB
    // x padded planes alias the (not-yet-written) H2/L2 region
    __half* Xh = (__half*)(wsb + (size_t)67108864);      // 8.39 MB
    __half* Xl = (__half*)(wsb + (size_t)75497472);      // 8.39 MB
    __half* H3 = (__half*)wsb;
    __half* L3 = (__half*)(wsb + (size_t)16777216);
    __half* H4 = (__half*)(wsb + (size_t)33554432);
    __half* L4 = (__half*)(wsb + (size_t)50331648);
    __half* Ht = (__half*)(wsb + (size_t)100663296);     // 4.19 MB
    __half* Lt = (__half*)(wsb + (size_t)104857600);     // 4.19 MB
    float*  EN = (float*)(wsb + (size_t)109051904);      // 2 KB
    __half* Fh = (__half*)wsb;
    __half* Fl = (__half*)(wsb + (size_t)16777216);
    bf16* Qb  = (bf16*)(wsb + (size_t)67108864);
    bf16* Db  = (bf16*)(wsb + (size_t)83886080);
    bf16* Y1b = Qb;
    bf16* Y2b = Db;
    bf16* Tb  = (bf16*)(wsb + (size_t)100663296);
    float* Y0 = (float*)wsb;
    float* Y1 = (float*)(wsb + (size_t)33554432);
    float* A1 = (float*)wsb;
    char* pk = wsb + (size_t)109056000;
    bf16* Pdec  = (bf16*)pk;  pk += 147456 * 2;
    bf16* Pd1w1 = (bf16*)pk;  pk += 36864 * 2;
    bf16* Pd1w2 = (bf16*)pk;  pk += 4096 * 2;
    bf16* Pd2w1 = (bf16*)pk;  pk += 36864 * 2;
    bf16* Pd2w2 = (bf16*)pk;  pk += 4096 * 2;
    bf16* Pdt1[4];
    for (int i = 0; i < 4; ++i) { Pdt1[i] = (bf16*)pk; pk += 65536 * 2; }
    __half* P2enc2 = (__half*)pk; pk += 131072 * 4;
    __half* P2enc3 = (__half*)pk; pk += 147456 * 4;
    __half* P2e1w1 = (__half*)pk; pk += 36864 * 4;
    __half* P2e1w2 = (__half*)pk; pk += 4096 * 4;
    __half* P2e2w1 = (__half*)pk; pk += 36864 * 4;
    __half* P2e2w2 = (__half*)pk; pk += 4096 * 4;
    __half* Pe     = (__half*)pk; pk += 131072 * 2;
    __half* Pe1    = (__half*)pk; pk += 8192 * 2;        // enc1 packed weights
    __half* Pdt2   = (__half*)pk; pk += 32768 * 2;       // dt2 packed weights (4 parities)

    float* outY = (float*)d_out;
    float* outF = outY + 3145728;
    float* outQ = outF + 8388608;

    const TapSet t3 = conv_taps(3, 3, 1);
    const TapSet t4 = conv_taps(4, 4, 1);
    const TapSet t1 = conv_taps(1, 1, 0);
    TapSet tdt[4];
    for (int p = 0; p < 4; ++p) tdt[p] = convt_taps(p >> 1, p & 1);

    enorm_k<<<2, 256, 0, stream>>>(emb, EN);
    pack_emb_k<<<256, 256, 0, stream>>>(emb, Pe);
    pack_we1_k<<<16, 256, 0, stream>>>(enc_w1, Pe1);
    pack_wdt2_k<<<64, 256, 0, stream>>>(dt2_w, Pdt2);

    // ---- weight packing (BN=128 for all Co=128 layers) ----
    pack_w_k<<<(147456 + 255) / 256, 256, 0, stream>>>(dec_w, Pdec, 128, 128, 128, t3, 147456);
    pack_w_k<<<(36864 + 255) / 256, 256, 0, stream>>>(drb1_w1, Pd1w1, 128, 32, 32, t3, 36864);
    pack_w_k<<<(4096 + 255) / 256, 256, 0, stream>>>(drb1_w2, Pd1w2, 32, 128, 128, t1, 4096);
    pack_w_k<<<(36864 + 255) / 256, 256, 0, stream>>>(drb2_w1, Pd2w1, 128, 32, 32, t3, 36864);
    pack_w_k<<<(4096 + 255) / 256, 256, 0, stream>>>(drb2_w2, Pd2w2, 32, 128, 128, t1, 4096);
    for (int p = 0; p < 4; ++p)
        pack_w_k<<<(65536 + 255) / 256, 256, 0, stream>>>(dt1_w, Pdt1[p], 128, 64, 64, tdt[p], 65536);
    pack_w2_k<<<(131072 + 255) / 256, 256, 0, stream>>>(enc_w2, P2enc2, 64, 128, 128, t4, 131072);
    pack_w2_k<<<(147456 + 255) / 256, 256, 0, stream>>>(enc_w3, P2enc3, 128, 128, 128, t3, 147456);
    pack_w2_k<<<(36864 + 255) / 256, 256, 0, stream>>>(erb1_w1, P2e1w1, 128, 32, 32, t3, 36864);
    pack_w2_k<<<(4096 + 255) / 256, 256, 0, stream>>>(erb1_w2, P2e1w2, 32, 128, 128, t1, 4096);
    pack_w2_k<<<(36864 + 255) / 256, 256, 0, stream>>>(erb2_w1, P2e2w1, 128, 32, 32, t3, 36864);
    pack_w2_k<<<(4096 + 255) / 256, 256, 0, stream>>>(erb2_w2, P2e2w2, 32, 128, 128, t1, 4096);

    // ---- encoder (fp16-split MFMA) ----
    pad_x_k<<<4096, 256, 0, stream>>>(x, Xh, Xl);
    enc1_mfma_k<<<4096, 256, 0, stream>>>(Xh, Xl, Pe1, enc_b1, H1, L1);
    conv_mfma2_k<128><<<dim3(1024, 1), 256, 0, stream>>>(H1, L1, P2enc2, enc_b2,
        nullptr, H2, L2, nullptr, nullptr, 128, 128, 64, 128, 2, t4, 16, F_OUTRELU);
    conv_mfma2_k<128><<<dim3(1024, 1), 256, 0, stream>>>(H2, L2, P2enc3, enc_b3,
        nullptr, H3, L3, nullptr, nullptr, 64, 64, 128, 128, 1, t3, 9, 0);
    conv_mfma2_k<32><<<dim3(1024, 1), 256, 0, stream>>>(H3, L3, P2e1w1, nullptr,
        nullptr, Ht, Lt, nullptr, nullptr, 64, 64, 128, 32, 1, t3, 9, F_INRELU);
    conv_mfma2_k<128><<<dim3(1024, 1), 256, 0, stream>>>(Ht, Lt, P2e1w2, nullptr,
        nullptr, H4, L4, H3, L3, 64, 64, 32, 128, 1, t1, 1, F_INRELU | F_RES);
    conv_mfma2_k<32><<<dim3(1024, 1), 256, 0, stream>>>(H4, L4, P2e2w1, nullptr,
        nullptr, Ht, Lt, nullptr, nullptr, 64, 64, 128, 32, 1, t3, 9, F_INRELU);
    conv_mfma2_k<128><<<dim3(1024, 1), 256, 0, stream>>>(Ht, Lt, P2e2w2, nullptr,
        outF, Fh, Fl, H4, L4, 64, 64, 32, 128, 1, t1, 1, F_INRELU | F_RES | F_OUTRELU);

    // ---- VQ ----
    vq_mfma_k<<<1024, 256, 0, stream>>>(Fh, Fl, Pe, EN, emb, outQ, Qb);

    // ---- decoder (bf16 MFMA) ----
    conv_mfma_k<128><<<dim3(1024, 1), 256, 0, stream>>>(Qb, Pdec, dec_b, Y0, Db, nullptr,
        128, 128, 64, 64, 1, 0, 0, t3, 9, 0);
    conv_mfma_k<32><<<dim3(1024, 1), 256, 0, stream>>>(Db, Pd1w1, nullptr, nullptr, Tb, nullptr,
        128, 32, 64, 64, 1, 0, 0, t3, 9, F_INRELU);
    conv_mfma_k<128><<<dim3(1024, 1), 256, 0, stream>>>(Tb, Pd1w2, nullptr, Y1, Y1b, Y0,
        32, 128, 64, 64, 1, 0, 0, t1, 1, F_INRELU | F_RES);
    conv_mfma_k<32><<<dim3(1024, 1), 256, 0, stream>>>(Y1b, Pd2w1, nullptr, nullptr, Tb, nullptr,
        128, 32, 64, 64, 1, 0, 0, t3, 9, F_INRELU);
    conv_mfma_k<128><<<dim3(1024, 1), 256, 0, stream>>>(Tb, Pd2w2, nullptr, nullptr, Y2b, Y1,
        32, 128, 64, 64, 1, 0, 0, t1, 1, F_INRELU | F_RES | F_OUTRELU);
    for (int p = 0; p < 4; ++p)
        conv_mfma_k<64><<<dim3(1024, 1), 256, 0, stream>>>(Y2b, Pdt1[p], dt1_b, A1, nullptr, nullptr,
            128, 64, 128, 128, 2, p >> 1, p & 1, tdt[p], 4, F_OUTRELU);

    // ---- dt2 (fp16 MFMA, A-hi only + B hi/lo: halved A-LDS traffic) ----
    dt2_mfma_k<<<16384, 256, 0, stream>>>(A1, Pdt2, dt2_b, outY);
}

// Round 14
// 789.635 us; speedup vs baseline: 1.0910x; 1.0167x over previous
//
#include <hip/hip_runtime.h>
#include <hip/hip_bf16.h>
#include <hip/hip_fp16.h>

using bf16 = __hip_bfloat16;
using frag_ab = __attribute__((ext_vector_type(8))) short;
using f16x8  = __attribute__((ext_vector_type(8))) _Float16;
using hf16x2 = __attribute__((ext_vector_type(2))) __fp16;   // cvt_pkrtz return type
using frag_cd = __attribute__((ext_vector_type(4))) float;

enum { F_INRELU = 1, F_OUTRELU = 2, F_RES = 4 };

struct TapSet { int dy[16]; int dx[16]; int wi[16]; };

__device__ __forceinline__ unsigned int relu_pk(unsigned int v) {
    unsigned int m = ((v & 0x80008000u) >> 15) * 0xFFFFu;
    return v & ~m;
}
__device__ __forceinline__ unsigned int mask_by(unsigned int v, unsigned int h) {
    unsigned int m = ((h & 0x80008000u) >> 15) * 0xFFFFu;
    return v & ~m;
}
// XCD-chunked swizzle: consecutive logical tiles land on the SAME XCD's L2
// (default dispatch round-robins blockIdx across 8 XCDs). Requires n % 8 == 0.
__device__ __forceinline__ int xcd_swz(int bx, int n) {
    return (bx & 7) * (n >> 3) + (bx >> 3);
}

// ---------------- weight pre-pack: bf16 (decoder) ----------------
__global__ void pack_w_k(const float* __restrict__ w, bf16* __restrict__ dst,
                         int Ci, int Co, int BN, TapSet taps, int total)
{
    int idx = blockIdx.x * 256 + threadIdx.x;
    if (idx >= total) return;
    int j  = idx & 7;
    int r1 = idx >> 3;
    int nl = r1 % BN;
    int r2 = r1 / BN;
    int q  = r2 & 3;
    int cb = r2 >> 2;
    int nblocks = Co / BN;
    int c  = cb / nblocks;
    int nb = cb - c * nblocks;
    int cpt = Ci >> 5;
    int tap = c / cpt;
    int ci  = (c - tap * cpt) * 32 + q * 8 + j;
    int n   = nb * BN + nl;
    dst[idx] = __float2bfloat16(w[(size_t)(taps.wi[tap] * Ci + ci) * Co + n]);
}

// ---------------- weight pre-pack: fp16 hi/lo split (encoder) ----------------
__global__ void pack_w2_k(const float* __restrict__ w, __half* __restrict__ dst,
                          int Ci, int Co, int BN, TapSet taps, int total)
{
    int idx = blockIdx.x * 256 + threadIdx.x;
    if (idx >= total) return;
    int j  = idx & 7;
    int r1 = idx >> 3;
    int nl = r1 % BN;
    int r2 = r1 / BN;
    int q  = r2 & 3;
    int cb = r2 >> 2;
    int nblocks = Co / BN;
    int c  = cb / nblocks;
    int nb = cb - c * nblocks;
    int cpt = Ci >> 5;
    int tap = c / cpt;
    int ci  = (c - tap * cpt) * 32 + q * 8 + j;
    int n   = nb * BN + nl;
    float v = w[(size_t)(taps.wi[tap] * Ci + ci) * Co + n];
    __half h = __float2half(v);
    __half l = __float2half((v - __half2float(h)) * 2048.0f);
    size_t base = (size_t)cb * (BN * 64) + (q * BN + nl) * 8 + j;
    dst[base] = h;
    dst[base + BN * 32] = l;
}

// ---------------- dt2 weight pack: (4,4,64,3) -> per-parity K=256, N=16 (pad), hi/lo ----
__global__ void pack_wdt2_k(const float* __restrict__ w, __half* __restrict__ dst)
{
    int idx = blockIdx.x * 256 + threadIdx.x;   // 16384
    if (idx >= 16384) return;
    int parity = idx >> 12;
    int r0 = idx & 4095;
    int j  = r0 & 7;
    int r1 = r0 >> 3;
    int nl = r1 & 15;
    int r2 = r1 >> 4;
    int q  = r2 & 3;
    int cb = r2 >> 2;                 // 0..7
    int tap = cb >> 1;
    int cc  = cb & 1;
    int ci  = cc * 32 + q * 8 + j;
    int n   = nl;
    int py = parity >> 1, px = parity & 1;
    int ty = tap >> 1, tx = tap & 1;
    int wi = (py + 2 * ty) * 4 + (px + 2 * tx);
    float v = (n < 3) ? w[(size_t)(wi * 64 + ci) * 3 + n] : 0.f;
    __half h = __float2half(v);
    __half l = __float2half((v - __half2float(h)) * 2048.0f);
    size_t base = (size_t)parity * 8192 + cb * 1024 + (q * 16 + nl) * 8 + j;
    dst[base] = h;
    dst[base + 512] = l;
}

// ---------------- enc1 weight pack: (4,4,3,64) -> K=64 (4th ch zero), hi/lo ----------------
__global__ void pack_we1_k(const float* __restrict__ w, __half* __restrict__ dst)
{
    int idx = blockIdx.x * 256 + threadIdx.x;   // 2*4*64*8 = 4096
    if (idx >= 4096) return;
    int j  = idx & 7;
    int r1 = idx >> 3;
    int nl = r1 & 63;
    int r2 = r1 >> 6;
    int q  = r2 & 3;
    int c  = r2 >> 2;                 // chunk 0/1
    int k  = c * 32 + q * 8 + j;
    int tap = k >> 2, ci = k & 3;
    float v = (ci < 3) ? w[(size_t)(tap * 3 + ci) * 64 + nl] : 0.f;
    __half h = __float2half(v);
    __half l = __float2half((v - __half2float(h)) * 2048.0f);
    size_t base = (size_t)c * 4096 + (q * 64 + nl) * 8 + j;
    dst[base] = h;
    dst[base + 2048] = l;
}

// ---------------- x pad: (16,256,256,3) fp32 -> (.,4) fp16 hi/lo ----------------
__global__ __launch_bounds__(256) void pad_x_k(
    const float* __restrict__ x, __half* __restrict__ xh, __half* __restrict__ xl)
{
    int pix = blockIdx.x * 256 + threadIdx.x;   // 1048576
    const float* ip = x + (size_t)pix * 3;
    float v0 = ip[0], v1 = ip[1], v2 = ip[2];
    unsigned short hb[4], lb[4];
    float vv[4] = {v0, v1, v2, 0.f};
#pragma unroll
    for (int i = 0; i < 4; ++i) {
        __half h = __float2half(vv[i]);
        hb[i] = __half_as_ushort(h);
        lb[i] = __half_as_ushort(__float2half((vv[i] - __half2float(h)) * 2048.0f));
    }
    uint2 hv = make_uint2((unsigned)hb[0] | ((unsigned)hb[1] << 16),
                          (unsigned)hb[2] | ((unsigned)hb[3] << 16));
    uint2 lv = make_uint2((unsigned)lb[0] | ((unsigned)lb[1] << 16),
                          (unsigned)lb[2] | ((unsigned)lb[3] << 16));
    *(uint2*)(xh + (size_t)pix * 4) = hv;
    *(uint2*)(xl + (size_t)pix * 4) = lv;
}

// ---------------- enc1: 4x4 s2, 4ch padded, fp16-split MFMA ----------------
__global__ __launch_bounds__(256) void enc1_mfma_k(
    const __half* __restrict__ xh, const __half* __restrict__ xl,
    const __half* __restrict__ wp, const float* __restrict__ bias,
    __half* __restrict__ oh, __half* __restrict__ ol)
{
    __shared__ __align__(16) short Ash[64 * 32];
    __shared__ __align__(16) short Asl[64 * 32];
    __shared__ __align__(16) short Bsh[64 * 32];
    __shared__ __align__(16) short Bsl[64 * 32];

    const int tid = threadIdx.x;
    const int m0 = xcd_swz(blockIdx.x, 4096) * 64;

    const int am = tid >> 2;
    const int aq = tid & 3;
    const int gm  = m0 + am;
    const int nn_ = gm >> 14;            // 128*128 pixels/image
    const int rr_ = gm & 16383;
    const int iy0 = (rr_ >> 7) * 2 - 1;
    const int ix0 = (rr_ & 127) * 2 - 1;

    const int lane = tid & 63;
    const int wv4 = tid >> 6;
    const int wm = (wv4 & 1) * 32;
    const int wn = (wv4 >> 1) * 32;
    const int lm = lane & 15, lq = lane >> 4;

    frag_cd accA[2][2], accB[2][2];
#pragma unroll
    for (int i = 0; i < 2; ++i)
#pragma unroll
        for (int j = 0; j < 2; ++j)
#pragma unroll
            for (int r = 0; r < 4; ++r) { accA[i][j][r] = 0.f; accB[i][j][r] = 0.f; }

#pragma unroll
    for (int c = 0; c < 2; ++c) {
        const int tap = c * 8 + aq * 2;
        const int ky = tap >> 2, kx = tap & 3;
        const int iy = iy0 + ky;
        const int ix = ix0 + kx;
        uint2 h0 = make_uint2(0u, 0u), h1 = h0, l0 = h0, l1 = h0;
        if (iy >= 0 && iy < 256) {
            const size_t rowb = (size_t)(nn_ * 256 + iy) * 256;
            if (ix >= 0 && ix < 256) {
                h0 = *(const uint2*)(xh + (rowb + ix) * 4);
                l0 = *(const uint2*)(xl + (rowb + ix) * 4);
            }
            if (ix + 1 >= 0 && ix + 1 < 256) {
                h1 = *(const uint2*)(xh + (rowb + ix + 1) * 4);
                l1 = *(const uint2*)(xl + (rowb + ix + 1) * 4);
            }
        }
        __syncthreads();
        *(uint4*)&Ash[(aq * 64 + am) * 8] = make_uint4(h0.x, h0.y, h1.x, h1.y);
        *(uint4*)&Asl[(aq * 64 + am) * 8] = make_uint4(l0.x, l0.y, l1.x, l1.y);
        {
            const __half* wc = wp + (size_t)c * 4096;
            *(uint4*)&Bsh[tid * 8] = *(const uint4*)(wc + tid * 8);
            *(uint4*)&Bsl[tid * 8] = *(const uint4*)(wc + 2048 + tid * 8);
        }
        __syncthreads();

        f16x8 afh[2], afl[2], bfh[2], bfl[2];
#pragma unroll
        for (int i = 0; i < 2; ++i) {
            afh[i] = *(const f16x8*)&Ash[(lq * 64 + wm + i * 16 + lm) * 8];
            afl[i] = *(const f16x8*)&Asl[(lq * 64 + wm + i * 16 + lm) * 8];
        }
#pragma unroll
        for (int j = 0; j < 2; ++j) {
            bfh[j] = *(const f16x8*)&Bsh[(lq * 64 + wn + j * 16 + lm) * 8];
            bfl[j] = *(const f16x8*)&Bsl[(lq * 64 + wn + j * 16 + lm) * 8];
        }
#pragma unroll
        for (int i = 0; i < 2; ++i)
#pragma unroll
            for (int j = 0; j < 2; ++j) {
                accA[i][j] = __builtin_amdgcn_mfma_f32_16x16x32_f16(afh[i], bfh[j], accA[i][j], 0, 0, 0);
                accB[i][j] = __builtin_amdgcn_mfma_f32_16x16x32_f16(afh[i], bfl[j], accB[i][j], 0, 0, 0);
                accB[i][j] = __builtin_amdgcn_mfma_f32_16x16x32_f16(afl[i], bfh[j], accB[i][j], 0, 0, 0);
            }
    }

    const float s = 1.0f / 2048.0f;
#pragma unroll
    for (int j = 0; j < 2; ++j) {
        const int n_g = wn + j * 16 + lm;
        const float bv = bias[n_g];
#pragma unroll
        for (int i = 0; i < 2; ++i) {
#pragma unroll
            for (int r = 0; r < 4; ++r) {
                const int m_g = m0 + wm + i * 16 + lq * 4 + r;
                const size_t ob = (size_t)m_g * 64 + n_g;
                float v = accA[i][j][r] + accB[i][j][r] * s + bv;
                v = fmaxf(v, 0.f);
                __half h = __float2half(v);
                oh[ob] = h;
                ol[ob] = __float2half((v - __half2float(h)) * 2048.0f);
            }
        }
    }
}

// ---------------- fp16-split MFMA implicit-GEMM conv (encoder) ----------------
// BN=128: one block covers ALL output channels -> A staged/fetched once (was 2x
// via gridDim.y=2) and 24 MFMA per barrier-pair (was 12).  Wave tile 32x64.
template<int BN>
__global__ __launch_bounds__(256) void conv_mfma2_k(
    const __half* __restrict__ ah, const __half* __restrict__ al,
    const __half* __restrict__ wp, const float* __restrict__ bias,
    float* __restrict__ out, __half* __restrict__ oh, __half* __restrict__ ol,
    const __half* __restrict__ rh, const __half* __restrict__ rl,
    int IH, int IW, int Ci, int Co, int sy_in,
    TapSet taps, int ntaps, int flags)
{
    __shared__ __align__(16) short Ash[64 * 32];
    __shared__ __align__(16) short Asl[64 * 32];
    __shared__ __align__(16) short Bsh[BN * 32];
    __shared__ __align__(16) short Bsl[BN * 32];

    const int tid = threadIdx.x;
    const int m0 = xcd_swz(blockIdx.x, gridDim.x) * 64;
    const int n0 = blockIdx.y * BN;

    const int am = tid >> 2;
    const int aq = tid & 3;
    const int gm  = m0 + am;
    const int nn_ = gm >> 12;
    const int rr_ = gm & 4095;
    const int oy_ = (rr_ >> 6) * sy_in;
    const int ox_ = (rr_ & 63) * sy_in;

    const int lane = tid & 63;
    const int wv4 = tid >> 6;
    constexpr int MT = (BN >= 64) ? 2 : 1;
    constexpr int NT = (BN == 128) ? 4 : 2;
    const int wm = (BN >= 64) ? (wv4 & 1) * 32 : wv4 * 16;
    const int wn = (BN == 128) ? (wv4 >> 1) * 64 : ((BN == 64) ? (wv4 >> 1) * 32 : 0);
    const int lm = lane & 15, lq = lane >> 4;
    constexpr int NLOAD = BN * 32 / 8;

    frag_cd accA[MT][NT], accB[MT][NT];
#pragma unroll
    for (int i = 0; i < MT; ++i)
#pragma unroll
        for (int j = 0; j < NT; ++j)
#pragma unroll
            for (int r = 0; r < 4; ++r) { accA[i][j][r] = 0.f; accB[i][j][r] = 0.f; }

    const int cpt = Ci >> 5;
    const int nch = ntaps * cpt;
    const bool inrelu = (flags & F_INRELU) != 0;

    int tap = 0, cc = 0, ci0 = 0;
    for (int c = 0; c < nch; ++c) {
        const int iy = oy_ + taps.dy[tap];
        const int ix = ox_ + taps.dx[tap];
        uint4 avh = make_uint4(0u, 0u, 0u, 0u);
        uint4 avl = make_uint4(0u, 0u, 0u, 0u);
        if (iy >= 0 && iy < IH && ix >= 0 && ix < IW) {
            const size_t off = (size_t)((nn_ * IH + iy) * IW + ix) * Ci + ci0 + aq * 8;
            avh = *(const uint4*)(ah + off);
            avl = *(const uint4*)(al + off);
        }
        if (inrelu) {
            avl.x = mask_by(avl.x, avh.x); avl.y = mask_by(avl.y, avh.y);
            avl.z = mask_by(avl.z, avh.z); avl.w = mask_by(avl.w, avh.w);
            avh.x = relu_pk(avh.x); avh.y = relu_pk(avh.y);
            avh.z = relu_pk(avh.z); avh.w = relu_pk(avh.w);
        }
        uint4 bvh0, bvl0, bvh1, bvl1;
        {
            const __half* wc = wp + (size_t)(c * gridDim.y + blockIdx.y) * (BN * 64);
            if constexpr (BN == 128) {
                bvh0 = *(const uint4*)(wc + tid * 8);
                bvh1 = *(const uint4*)(wc + (256 + tid) * 8);
                bvl0 = *(const uint4*)(wc + BN * 32 + tid * 8);
                bvl1 = *(const uint4*)(wc + BN * 32 + (256 + tid) * 8);
            } else if (tid < NLOAD) {
                bvh0 = *(const uint4*)(wc + tid * 8);
                bvl0 = *(const uint4*)(wc + BN * 32 + tid * 8);
            }
        }

        __syncthreads();
        *(uint4*)&Ash[(aq * 64 + am) * 8] = avh;
        *(uint4*)&Asl[(aq * 64 + am) * 8] = avl;
        if constexpr (BN == 128) {
            *(uint4*)&Bsh[tid * 8] = bvh0;
            *(uint4*)&Bsh[(256 + tid) * 8] = bvh1;
            *(uint4*)&Bsl[tid * 8] = bvl0;
            *(uint4*)&Bsl[(256 + tid) * 8] = bvl1;
        } else if (tid < NLOAD) {
            *(uint4*)&Bsh[tid * 8] = bvh0;
            *(uint4*)&Bsl[tid * 8] = bvl0;
        }
        __syncthreads();

        f16x8 afh[MT], afl[MT], bfh[NT], bfl[NT];
#pragma unroll
        for (int i = 0; i < MT; ++i) {
            afh[i] = *(const f16x8*)&Ash[(lq * 64 + wm + i * 16 + lm) * 8];
            afl[i] = *(const f16x8*)&Asl[(lq * 64 + wm + i * 16 + lm) * 8];
        }
#pragma unroll
        for (int j = 0; j < NT; ++j) {
            bfh[j] = *(const f16x8*)&Bsh[(lq * BN + wn + j * 16 + lm) * 8];
            bfl[j] = *(const f16x8*)&Bsl[(lq * BN + wn + j * 16 + lm) * 8];
        }
#pragma unroll
        for (int i = 0; i < MT; ++i)
#pragma unroll
            for (int j = 0; j < NT; ++j) {
                accA[i][j] = __builtin_amdgcn_mfma_f32_16x16x32_f16(afh[i], bfh[j], accA[i][j], 0, 0, 0);
                accB[i][j] = __builtin_amdgcn_mfma_f32_16x16x32_f16(afh[i], bfl[j], accB[i][j], 0, 0, 0);
                accB[i][j] = __builtin_amdgcn_mfma_f32_16x16x32_f16(afl[i], bfh[j], accB[i][j], 0, 0, 0);
            }

        ci0 += 32;
        if (++cc == cpt) { cc = 0; ci0 = 0; ++tap; }
    }

    const float s = 1.0f / 2048.0f;
#pragma unroll
    for (int j = 0; j < NT; ++j) {
        const int n_g = n0 + wn + j * 16 + lm;
        const float bv = bias ? bias[n_g] : 0.f;
#pragma unroll
        for (int i = 0; i < MT; ++i) {
#pragma unroll
            for (int r = 0; r < 4; ++r) {
                const int m_g = m0 + wm + i * 16 + lq * 4 + r;
                const size_t ob = (size_t)m_g * Co + n_g;
                float v = accA[i][j][r] + accB[i][j][r] * s + bv;
                if (flags & F_RES)
                    v += __half2float(rh[ob]) + __half2float(rl[ob]) * s;
                if (flags & F_OUTRELU) v = fmaxf(v, 0.f);
                if (out) out[ob] = v;
                if (oh) {
                    __half h = __float2half(v);
                    oh[ob] = h;
                    ol[ob] = __float2half((v - __half2float(h)) * 2048.0f);
                }
            }
        }
    }
}

// ---------------- bf16 MFMA implicit-GEMM conv (decoder) ----------------
template<int BN>
__global__ __launch_bounds__(256) void conv_mfma_k(
    const bf16* __restrict__ a, const bf16* __restrict__ wp,
    const float* __restrict__ bias,
    float* __restrict__ out, bf16* __restrict__ out_bf,
    const float* __restrict__ res,
    int Ci, int Co, int OHf, int OWf, int sy_out, int py, int px,
    TapSet taps, int ntaps, int flags)
{
    __shared__ __align__(16) short As[64 * 32];
    __shared__ __align__(16) short Bs[BN * 32];

    const int tid = threadIdx.x;
    const int m0 = xcd_swz(blockIdx.x, gridDim.x) * 64;
    const int n0 = blockIdx.y * BN;

    const int am = tid >> 2;
    const int aq = tid & 3;
    const int gm  = m0 + am;
    const int nn_ = gm >> 12;
    const int rr_ = gm & 4095;
    const int oy_ = rr_ >> 6;
    const int ox_ = rr_ & 63;

    const int lane = tid & 63;
    const int wv4 = tid >> 6;
    constexpr int MT = (BN >= 64) ? 2 : 1;
    constexpr int NT = (BN == 128) ? 4 : 2;
    const int wm = (BN >= 64) ? (wv4 & 1) * 32 : wv4 * 16;
    const int wn = (BN == 128) ? (wv4 >> 1) * 64 : ((BN == 64) ? (wv4 >> 1) * 32 : 0);
    const int lm = lane & 15, lq = lane >> 4;
    constexpr int NLOAD = BN * 32 / 8;

    frag_cd acc[MT][NT];
#pragma unroll
    for (int i = 0; i < MT; ++i)
#pragma unroll
        for (int j = 0; j < NT; ++j)
#pragma unroll
            for (int r = 0; r < 4; ++r) acc[i][j][r] = 0.f;

    const int cpt = Ci >> 5;
    const int nch = ntaps * cpt;
    const bool inrelu = (flags & F_INRELU) != 0;

    int tap = 0, cc = 0, ci0 = 0;
    for (int c = 0; c < nch; ++c) {
        const int iy = oy_ + taps.dy[tap];
        const int ix = ox_ + taps.dx[tap];
        uint4 av = make_uint4(0u, 0u, 0u, 0u);
        if (iy >= 0 && iy < 64 && ix >= 0 && ix < 64)
            av = *(const uint4*)(a + (size_t)((nn_ * 64 + iy) * 64 + ix) * Ci + ci0 + aq * 8);
        if (inrelu) {
            av.x = relu_pk(av.x); av.y = relu_pk(av.y);
            av.z = relu_pk(av.z); av.w = relu_pk(av.w);
        }
        uint4 bv0, bv1;
        {
            const bf16* wc = wp + ((size_t)c * gridDim.y + blockIdx.y) * (BN * 32);
            if constexpr (BN == 128) {
                bv0 = *(const uint4*)(wc + tid * 8);
                bv1 = *(const uint4*)(wc + (256 + tid) * 8);
            } else if (tid < NLOAD) {
                bv0 = *(const uint4*)(wc + tid * 8);
            }
        }

        __syncthreads();
        *(uint4*)&As[(aq * 64 + am) * 8] = av;
        if constexpr (BN == 128) {
            *(uint4*)&Bs[tid * 8] = bv0;
            *(uint4*)&Bs[(256 + tid) * 8] = bv1;
        } else if (tid < NLOAD) {
            *(uint4*)&Bs[tid * 8] = bv0;
        }
        __syncthreads();

        frag_ab af[MT], bfr[NT];
#pragma unroll
        for (int i = 0; i < MT; ++i)
            af[i] = *(const frag_ab*)&As[(lq * 64 + wm + i * 16 + lm) * 8];
#pragma unroll
        for (int j = 0; j < NT; ++j)
            bfr[j] = *(const frag_ab*)&Bs[(lq * BN + wn + j * 16 + lm) * 8];
#pragma unroll
        for (int i = 0; i < MT; ++i)
#pragma unroll
            for (int j = 0; j < NT; ++j)
                acc[i][j] = __builtin_amdgcn_mfma_f32_16x16x32_bf16(af[i], bfr[j], acc[i][j], 0, 0, 0);

        ci0 += 32;
        if (++cc == cpt) { cc = 0; ci0 = 0; ++tap; }
    }

#pragma unroll
    for (int j = 0; j < NT; ++j) {
        const int n_g = n0 + wn + j * 16 + lm;
        const float bv = bias ? bias[n_g] : 0.f;
#pragma unroll
        for (int i = 0; i < MT; ++i) {
#pragma unroll
            for (int r = 0; r < 4; ++r) {
                const int m_g = m0 + wm + i * 16 + lq * 4 + r;
                const int nn2 = m_g >> 12;
                const int rr2 = m_g & 4095;
                const int oy = (rr2 >> 6) * sy_out + py;
                const int ox = (rr2 & 63) * sy_out + px;
                const size_t ob = ((size_t)(nn2 * OHf + oy) * OWf + ox) * Co + n_g;
                float v = acc[i][j][r] + bv;
                if (flags & F_RES)     v += res[ob];
                if (flags & F_OUTRELU) v = fmaxf(v, 0.f);
                if (out)    out[ob]    = v;
                if (out_bf) out_bf[ob] = __float2bfloat16(v);
            }
        }
    }
}

// ---------------- fused decoder residual block: 3x3 128->32 + 1x1 32->128 + res ------
// ResidualBlock: out = x + Conv1x1(relu(Conv3x3(relu(x)))).  The 1x1's entire input
// (this block's 64 pixels x 32 ch) is exactly phase 1's accumulator -> fuse:
// phase 1 = conv_mfma_k<32> body (INRELU); relu(acc)->bf16 into LDS T[64][32]
// (bitwise identical to the old Tb global round-trip: bf16(relu(v)) == relu_pk(bf16(v)));
// phase 2 = one-chunk 1x1 GEMM (K=32, N=128, 8 MFMA/wave) + residual + stores.
// Eliminates 2 kernel launches and the Tb write+read per pair.
__global__ __launch_bounds__(256) void dres_k(
    const bf16* __restrict__ a,        // input (64x64x128 bf16)
    const bf16* __restrict__ w3,       // packed 3x3 128->32 (BN=32 layout)
    const bf16* __restrict__ w1,       // packed 1x1 32->128 (BN=128 layout, 4096 elems)
    const float* __restrict__ res,     // residual (64x64x128 fp32)
    float* __restrict__ out,           // optional fp32 out
    bf16* __restrict__ out_bf,         // bf16 out
    TapSet taps, int outrelu)
{
    __shared__ __align__(16) short As[64 * 32];
    __shared__ __align__(16) short Bs[32 * 32];
    __shared__ __align__(16) short Bs2[32 * 128];
    __shared__ bf16 Tsh[64 * 32];

    const int tid = threadIdx.x;
    const int m0 = xcd_swz(blockIdx.x, gridDim.x) * 64;

    const int am = tid >> 2;
    const int aq = tid & 3;
    const int gm  = m0 + am;
    const int nn_ = gm >> 12;
    const int rr_ = gm & 4095;
    const int oy_ = rr_ >> 6;
    const int ox_ = rr_ & 63;

    const int lane = tid & 63;
    const int wv4 = tid >> 6;
    const int wm = wv4 * 16;
    const int lm = lane & 15, lq = lane >> 4;

    // stage 1x1 weights once (4096 bf16 = 8KB); visible after first barrier
    *(uint4*)&Bs2[tid * 8] = *(const uint4*)(w1 + tid * 8);
    *(uint4*)&Bs2[(256 + tid) * 8] = *(const uint4*)(w1 + (256 + tid) * 8);

    frag_cd acc[2];
#pragma unroll
    for (int j = 0; j < 2; ++j)
#pragma unroll
        for (int r = 0; r < 4; ++r) acc[j][r] = 0.f;

    for (int c = 0; c < 36; ++c) {
        const int tap = c >> 2;
        const int ci0 = (c & 3) * 32;
        const int iy = oy_ + taps.dy[tap];
        const int ix = ox_ + taps.dx[tap];
        uint4 av = make_uint4(0u, 0u, 0u, 0u);
        if (iy >= 0 && iy < 64 && ix >= 0 && ix < 64)
            av = *(const uint4*)(a + (size_t)((nn_ * 64 + iy) * 64 + ix) * 128 + ci0 + aq * 8);
        av.x = relu_pk(av.x); av.y = relu_pk(av.y);
        av.z = relu_pk(av.z); av.w = relu_pk(av.w);
        uint4 bv;
        if (tid < 128)
            bv = *(const uint4*)(w3 + (size_t)c * 1024 + tid * 8);

        __syncthreads();
        *(uint4*)&As[(aq * 64 + am) * 8] = av;
        if (tid < 128) *(uint4*)&Bs[tid * 8] = bv;
        __syncthreads();

        const frag_ab af = *(const frag_ab*)&As[(lq * 64 + wm + lm) * 8];
#pragma unroll
        for (int j = 0; j < 2; ++j) {
            const frag_ab bfr = *(const frag_ab*)&Bs[(lq * 32 + j * 16 + lm) * 8];
            acc[j] = __builtin_amdgcn_mfma_f32_16x16x32_bf16(af, bfr, acc[j], 0, 0, 0);
        }
    }

    // phase 2: T = bf16(relu(acc)) -> LDS; 1x1 GEMM; +res; store
#pragma unroll
    for (int j = 0; j < 2; ++j)
#pragma unroll
        for (int r = 0; r < 4; ++r)
            Tsh[(wm + lq * 4 + r) * 32 + j * 16 + lm] =
                __float2bfloat16(fmaxf(acc[j][r], 0.f));
    __syncthreads();

    const frag_ab af2 = *(const frag_ab*)&Tsh[(wm + lm) * 32 + lq * 8];
    frag_cd acc2[8];
#pragma unroll
    for (int j = 0; j < 8; ++j) {
#pragma unroll
        for (int r = 0; r < 4; ++r) acc2[j][r] = 0.f;
        const frag_ab bfr2 = *(const frag_ab*)&Bs2[(lq * 128 + j * 16 + lm) * 8];
        acc2[j] = __builtin_amdgcn_mfma_f32_16x16x32_bf16(af2, bfr2, acc2[j], 0, 0, 0);
    }

#pragma unroll
    for (int j = 0; j < 8; ++j) {
        const int n_g = j * 16 + lm;
#pragma unroll
        for (int r = 0; r < 4; ++r) {
            const int m_g = m0 + wm + lq * 4 + r;
            const size_t ob = (size_t)m_g * 128 + n_g;
            float v = acc2[j][r] + res[ob];
            if (outrelu) v = fmaxf(v, 0.f);
            if (out) out[ob] = v;
            out_bf[ob] = __float2bfloat16(v);
        }
    }
}

// ---------------- dt2: convT 4x4 s2, 64->3 via fp16 MFMA (A-hi only) -------------
__global__ __launch_bounds__(256) void dt2_mfma_k(
    const float* __restrict__ in,      // A1: (16,128,128,64) fp32, relu'd
    const __half* __restrict__ wp,     // packed per-parity weights (4 x 8192 halves)
    const float* __restrict__ bias,    // 3
    float* __restrict__ out)           // (16,256,256,3)
{
    __shared__ __align__(16) short Ash[2][64 * 32];
    __shared__ __align__(16) short Bsh[2][16 * 32];
    __shared__ __align__(16) short Bsl[2][16 * 32];

    const int tid = threadIdx.x;
    const int bx  = xcd_swz(blockIdx.x, 16384);   // parity quads stay on one XCD
    const int par = bx & 3;
    const int m0  = (bx >> 2) * 64;
    const int py = par >> 1, px = par & 1;

    const int am = tid >> 2;
    const int aq = tid & 3;
    const int gm  = m0 + am;
    const int nn_ = gm >> 14;            // image
    const int rr_ = gm & 16383;
    const int r_  = rr_ >> 7;            // 0..127
    const int c_  = rr_ & 127;

    const int lane = tid & 63;
    const int wv4 = tid >> 6;
    const int wm = wv4 * 16;
    const int lm = lane & 15, lq = lane >> 4;

    frag_cd accA, accB;
#pragma unroll
    for (int r = 0; r < 4; ++r) { accA[r] = 0.f; accB[r] = 0.f; }

    const __half* wpar = wp + (size_t)par * 8192;

    for (int t = 0; t < 4; ++t) {
        const int iy = r_ + py + (t >> 1) - 1;
        const int ix = c_ + px + (t & 1) - 1;
        uint4 hi0 = make_uint4(0u, 0u, 0u, 0u), hi1 = hi0;
        if ((unsigned)iy < 128u && (unsigned)ix < 128u) {
            const float* ip = in + (size_t)((nn_ * 128 + iy) * 128 + ix) * 64 + aq * 8;
#pragma unroll
            for (int h = 0; h < 2; ++h) {
                const float4 v0 = *(const float4*)(ip + h * 32);
                const float4 v1 = *(const float4*)(ip + h * 32 + 4);
                union { hf16x2 p[4]; uint4 u; } uh;
                uh.p[0] = __builtin_amdgcn_cvt_pkrtz(v0.x, v0.y);
                uh.p[1] = __builtin_amdgcn_cvt_pkrtz(v0.z, v0.w);
                uh.p[2] = __builtin_amdgcn_cvt_pkrtz(v1.x, v1.y);
                uh.p[3] = __builtin_amdgcn_cvt_pkrtz(v1.z, v1.w);
                if (h == 0) hi0 = uh.u; else hi1 = uh.u;
            }
        }
        uint4 bvh, bvl;
        if (tid < 128) {
            const __half* wc = wpar + (size_t)(2 * t + (tid >> 6)) * 1024 + (tid & 63) * 8;
            bvh = *(const uint4*)wc;
            bvl = *(const uint4*)(wc + 512);
        }

        __syncthreads();
        *(uint4*)&Ash[0][(aq * 64 + am) * 8] = hi0;
        *(uint4*)&Ash[1][(aq * 64 + am) * 8] = hi1;
        if (tid < 128) {
            *(uint4*)&Bsh[tid >> 6][(tid & 63) * 8] = bvh;
            *(uint4*)&Bsl[tid >> 6][(tid & 63) * 8] = bvl;
        }
        __syncthreads();

#pragma unroll
        for (int h = 0; h < 2; ++h) {
            const f16x8 afh = *(const f16x8*)&Ash[h][(lq * 64 + wm + lm) * 8];
            const f16x8 bfh = *(const f16x8*)&Bsh[h][(lq * 16 + lm) * 8];
            const f16x8 bfl = *(const f16x8*)&Bsl[h][(lq * 16 + lm) * 8];
            accA = __builtin_amdgcn_mfma_f32_16x16x32_f16(afh, bfh, accA, 0, 0, 0);
            accB = __builtin_amdgcn_mfma_f32_16x16x32_f16(afh, bfl, accB, 0, 0, 0);
        }
    }

    const float s = 1.0f / 2048.0f;
    if (lm < 3) {
        const float bv = bias[lm];
#pragma unroll
        for (int r = 0; r < 4; ++r) {
            const int m_g = m0 + wm + lq * 4 + r;
            const int nn2 = m_g >> 14;
            const int rr2 = m_g & 16383;
            const int oy = (rr2 >> 7) * 2 + py;
            const int ox = (rr2 & 127) * 2 + px;
            out[((size_t)(nn2 * 256 + oy) * 256 + ox) * 3 + lm] = accA[r] + accB[r] * s + bv;
        }
    }
}

// ---------------- VQ ----------------
__global__ void enorm_k(const float* __restrict__ emb, float* __restrict__ en) {
    int k = blockIdx.x * 256 + threadIdx.x;
    if (k >= 512) return;
    const float4* e = (const float4*)(emb + k * 128);
    float s = 0.f;
    for (int i = 0; i < 32; ++i) {
        float4 v = e[i];
        s += v.x * v.x + v.y * v.y + v.z * v.z + v.w * v.w;
    }
    en[k] = s;
}

__global__ void pack_emb_k(const float* __restrict__ emb, __half* __restrict__ dst)
{
    int idx = blockIdx.x * 256 + threadIdx.x;   // 65536
    int k = idx & 127;
    int n = idx >> 7;
    float v = emb[idx];
    __half h = __float2half(v);
    __half l = __float2half((v - __half2float(h)) * 2048.0f);
    int nb = n >> 6, nl = n & 63;
    int ch = k >> 5, q = (k >> 3) & 3, j = k & 7;
    size_t base = (size_t)(nb * 4 + ch) * 4096 + (q * 64 + nl) * 8 + j;
    dst[base] = h;
    dst[base + 2048] = l;
}

__global__ __launch_bounds__(256) void vq_mfma_k(
    const __half* __restrict__ fh, const __half* __restrict__ fl,
    const __half* __restrict__ pe, const float* __restrict__ en,
    const float* __restrict__ emb, float* __restrict__ q, bf16* __restrict__ qb)
{
    __shared__ __align__(16) short Ash[64 * 128];
    __shared__ __align__(16) short Asl[64 * 128];
    __shared__ int sel[64];

    const int tid  = threadIdx.x;
    const int pos0 = blockIdx.x * 64;

    {
        const int am = tid >> 2;
        const int aq = tid & 3;
#pragma unroll
        for (int ch = 0; ch < 4; ++ch) {
            const size_t off = (size_t)(pos0 + am) * 128 + ch * 32 + aq * 8;
            uint4 vh = *(const uint4*)(fh + off);
            uint4 vl = *(const uint4*)(fl + off);
            *(uint4*)&Ash[((ch * 4 + aq) * 64 + am) * 8] = vh;
            *(uint4*)&Asl[((ch * 4 + aq) * 64 + am) * 8] = vl;
        }
    }
    __syncthreads();

    const int lane = tid & 63;
    const int w    = tid >> 6;
    const int lm = lane & 15, lq = lane >> 4;
    const int mbase = w * 16;
    const float s = 1.0f / 2048.0f;

    float best[4] = {3.4e38f, 3.4e38f, 3.4e38f, 3.4e38f};
    int   bidx[4] = {0, 0, 0, 0};

    f16x8 ah[4], alv[4];
#pragma unroll
    for (int ch = 0; ch < 4; ++ch) {
        ah[ch]  = *(const f16x8*)&Ash[((ch * 4 + lq) * 64 + mbase + lm) * 8];
        alv[ch] = *(const f16x8*)&Asl[((ch * 4 + lq) * 64 + mbase + lm) * 8];
    }

    for (int nb = 0; nb < 8; ++nb) {
        frag_cd accA[4], accB[4];
#pragma unroll
        for (int j = 0; j < 4; ++j)
#pragma unroll
            for (int r = 0; r < 4; ++r) { accA[j][r] = 0.f; accB[j][r] = 0.f; }

#pragma unroll
        for (int ch = 0; ch < 4; ++ch) {
            const __half* base = pe + (size_t)(nb * 4 + ch) * 4096;
            f16x8 bh[4], bl[4];
#pragma unroll
            for (int j = 0; j < 4; ++j) {
                const int o = (lq * 64 + j * 16 + lm) * 8;
                bh[j] = *(const f16x8*)(base + o);
                bl[j] = *(const f16x8*)(base + 2048 + o);
            }
#pragma unroll
            for (int j = 0; j < 4; ++j) {
                accA[j] = __builtin_amdgcn_mfma_f32_16x16x32_f16(ah[ch], bh[j], accA[j], 0, 0, 0);
                accB[j] = __builtin_amdgcn_mfma_f32_16x16x32_f16(ah[ch], bl[j], accB[j], 0, 0, 0);
                accB[j] = __builtin_amdgcn_mfma_f32_16x16x32_f16(alv[ch], bh[j], accB[j], 0, 0, 0);
            }
        }

#pragma unroll
        for (int j = 0; j < 4; ++j) {
            const int code = nb * 64 + j * 16 + lm;
            const float ec = en[code];
#pragma unroll
            for (int r = 0; r < 4; ++r) {
                float dot = accA[j][r] + accB[j][r] * s;
                float d = fmaf(dot, -2.f, ec);
                if (d < best[r]) { best[r] = d; bidx[r] = code; }
            }
        }
    }

#pragma unroll
    for (int r = 0; r < 4; ++r) {
        float d = best[r]; int ix = bidx[r];
#pragma unroll
        for (int m = 1; m < 16; m <<= 1) {
            float d2 = __shfl_xor(d, m);
            int   x2 = __shfl_xor(ix, m);
            if (d2 < d || (d2 == d && x2 < ix)) { d = d2; ix = x2; }
        }
        if (lm == 0) sel[mbase + lq * 4 + r] = ix;
    }
    __syncthreads();

#pragma unroll
    for (int jj = 0; jj < 32; ++jj) {
        int id = jj * 256 + tid;
        int p = id >> 7, k = id & 127;
        float v = emb[(size_t)sel[p] * 128 + k];
        q[(size_t)(pos0 + p) * 128 + k]  = v;
        qb[(size_t)(pos0 + p) * 128 + k] = __float2bfloat16(v);
    }
}

// ---------------- host ----------------
static TapSet conv_taps(int KH, int KW, int pad) {
    TapSet t{};
    for (int ky = 0; ky < KH; ++ky)
        for (int kx = 0; kx < KW; ++kx) {
            int i = ky * KW + kx;
            t.dy[i] = ky - pad; t.dx[i] = kx - pad; t.wi[i] = i;
        }
    return t;
}

static TapSet convt_taps(int py, int px) {
    TapSet t{};
    for (int ty = 0; ty < 2; ++ty)
        for (int tx = 0; tx < 2; ++tx) {
            int i = ty * 2 + tx;
            t.dy[i] = py + ty - 1;
            t.dx[i] = px + tx - 1;
            t.wi[i] = (py + 2 * ty) * 4 + (px + 2 * tx);
        }
    return t;
}

extern "C" void kernel_launch(void* const* d_in, const int* in_sizes, int n_in,
                              void* d_out, int out_size, void* d_ws, size_t ws_size,
                              hipStream_t stream)
{
    const float* x       = (const float*)d_in[0];
    const float* emb     = (const float*)d_in[1];
    const float* enc_w1  = (const float*)d_in[2];
    const float* enc_b1  = (const float*)d_in[3];
    const float* enc_w2  = (const float*)d_in[4];
    const float* enc_b2  = (const float*)d_in[5];
    const float* enc_w3  = (const float*)d_in[6];
    const float* enc_b3  = (const float*)d_in[7];
    const float* erb1_w1 = (const float*)d_in[8];
    const float* erb1_w2 = (const float*)d_in[9];
    const float* erb2_w1 = (const float*)d_in[10];
    const float* erb2_w2 = (const float*)d_in[11];
    const float* dec_w   = (const float*)d_in[12];
    const float* dec_b   = (const float*)d_in[13];
    const float* drb1_w1 = (const float*)d_in[14];
    const float* drb1_w2 = (const float*)d_in[15];
    const float* drb2_w1 = (const float*)d_in[16];
    const float* drb2_w2 = (const float*)d_in[17];
    const float* dt1_w   = (const float*)d_in[18];
    const float* dt1_b   = (const float*)d_in[19];
    const float* dt2_w   = (const float*)d_in[20];
    const float* dt2_b   = (const float*)d_in[21];

    char* wsb = (char*)d_ws;
    __half* H1 = (__half*)wsb;                           // 33.55 MB
    __half* L1 = (__half*)(wsb + (size_t)33554432);      // 33.55 MB
    __half* H2 = (__half*)(wsb + (size_t)67108864);      // 16.78 MB
    __half* L2 = (__half*)(wsb + (size_t)83886080);      // 16.78 MB
    // x padded planes alias the (not-yet-written) H2/L2 region
    __half* Xh = (__half*)(wsb + (size_t)67108864);      // 8.39 MB
    __half* Xl = (__half*)(wsb + (size_t)75497472);      // 8.39 MB
    __half* H3 = (__half*)wsb;
    __half* L3 = (__half*)(wsb + (size_t)16777216);
    __half* H4 = (__half*)(wsb + (size_t)33554432);
    __half* L4 = (__half*)(wsb + (size_t)50331648);
    __half* Ht = (__half*)(wsb + (size_t)100663296);     // 4.19 MB
    __half* Lt = (__half*)(wsb + (size_t)104857600);     // 4.19 MB
    float*  EN = (float*)(wsb + (size_t)109051904);      // 2 KB
    __half* Fh = (__half*)wsb;
    __half* Fl = (__half*)(wsb + (size_t)16777216);
    bf16* Qb  = (bf16*)(wsb + (size_t)67108864);
    bf16* Db  = (bf16*)(wsb + (size_t)83886080);
    bf16* Y1b = Qb;
    bf16* Y2b = Db;
    float* Y0 = (float*)wsb;
    float* Y1 = (float*)(wsb + (size_t)33554432);
    float* A1 = (float*)wsb;
    char* pk = wsb + (size_t)109056000;
    bf16* Pdec  = (bf16*)pk;  pk += 147456 * 2;
    bf16* Pd1w1 = (bf16*)pk;  pk += 36864 * 2;
    bf16* Pd1w2 = (bf16*)pk;  pk += 4096 * 2;
    bf16* Pd2w1 = (bf16*)pk;  pk += 36864 * 2;
    bf16* Pd2w2 = (bf16*)pk;  pk += 4096 * 2;
    bf16* Pdt1[4];
    for (int i = 0; i < 4; ++i) { Pdt1[i] = (bf16*)pk; pk += 65536 * 2; }
    __half* P2enc2 = (__half*)pk; pk += 131072 * 4;
    __half* P2enc3 = (__half*)pk; pk += 147456 * 4;
    __half* P2e1w1 = (__half*)pk; pk += 36864 * 4;
    __half* P2e1w2 = (__half*)pk; pk += 4096 * 4;
    __half* P2e2w1 = (__half*)pk; pk += 36864 * 4;
    __half* P2e2w2 = (__half*)pk; pk += 4096 * 4;
    __half* Pe     = (__half*)pk; pk += 131072 * 2;
    __half* Pe1    = (__half*)pk; pk += 8192 * 2;        // enc1 packed weights
    __half* Pdt2   = (__half*)pk; pk += 32768 * 2;       // dt2 packed weights (4 parities)

    float* outY = (float*)d_out;
    float* outF = outY + 3145728;
    float* outQ = outF + 8388608;

    const TapSet t3 = conv_taps(3, 3, 1);
    const TapSet t4 = conv_taps(4, 4, 1);
    const TapSet t1 = conv_taps(1, 1, 0);
    TapSet tdt[4];
    for (int p = 0; p < 4; ++p) tdt[p] = convt_taps(p >> 1, p & 1);

    enorm_k<<<2, 256, 0, stream>>>(emb, EN);
    pack_emb_k<<<256, 256, 0, stream>>>(emb, Pe);
    pack_we1_k<<<16, 256, 0, stream>>>(enc_w1, Pe1);
    pack_wdt2_k<<<64, 256, 0, stream>>>(dt2_w, Pdt2);

    // ---- weight packing (BN=128 for all Co=128 layers) ----
    pack_w_k<<<(147456 + 255) / 256, 256, 0, stream>>>(dec_w, Pdec, 128, 128, 128, t3, 147456);
    pack_w_k<<<(36864 + 255) / 256, 256, 0, stream>>>(drb1_w1, Pd1w1, 128, 32, 32, t3, 36864);
    pack_w_k<<<(4096 + 255) / 256, 256, 0, stream>>>(drb1_w2, Pd1w2, 32, 128, 128, t1, 4096);
    pack_w_k<<<(36864 + 255) / 256, 256, 0, stream>>>(drb2_w1, Pd2w1, 128, 32, 32, t3, 36864);
    pack_w_k<<<(4096 + 255) / 256, 256, 0, stream>>>(drb2_w2, Pd2w2, 32, 128, 128, t1, 4096);
    for (int p = 0; p < 4; ++p)
        pack_w_k<<<(65536 + 255) / 256, 256, 0, stream>>>(dt1_w, Pdt1[p], 128, 64, 64, tdt[p], 65536);
    pack_w2_k<<<(131072 + 255) / 256, 256, 0, stream>>>(enc_w2, P2enc2, 64, 128, 128, t4, 131072);
    pack_w2_k<<<(147456 + 255) / 256, 256, 0, stream>>>(enc_w3, P2enc3, 128, 128, 128, t3, 147456);
    pack_w2_k<<<(36864 + 255) / 256, 256, 0, stream>>>(erb1_w1, P2e1w1, 128, 32, 32, t3, 36864);
    pack_w2_k<<<(4096 + 255) / 256, 256, 0, stream>>>(erb1_w2, P2e1w2, 32, 128, 128, t1, 4096);
    pack_w2_k<<<(36864 + 255) / 256, 256, 0, stream>>>(erb2_w1, P2e2w1, 128, 32, 32, t3, 36864);
    pack_w2_k<<<(4096 + 255) / 256, 256, 0, stream>>>(erb2_w2, P2e2w2, 32, 128, 128, t1, 4096);

    // ---- encoder (fp16-split MFMA) ----
    pad_x_k<<<4096, 256, 0, stream>>>(x, Xh, Xl);
    enc1_mfma_k<<<4096, 256, 0, stream>>>(Xh, Xl, Pe1, enc_b1, H1, L1);
    conv_mfma2_k<128><<<dim3(1024, 1), 256, 0, stream>>>(H1, L1, P2enc2, enc_b2,
        nullptr, H2, L2, nullptr, nullptr, 128, 128, 64, 128, 2, t4, 16, F_OUTRELU);
    conv_mfma2_k<128><<<dim3(1024, 1), 256, 0, stream>>>(H2, L2, P2enc3, enc_b3,
        nullptr, H3, L3, nullptr, nullptr, 64, 64, 128, 128, 1, t3, 9, 0);
    conv_mfma2_k<32><<<dim3(1024, 1), 256, 0, stream>>>(H3, L3, P2e1w1, nullptr,
        nullptr, Ht, Lt, nullptr, nullptr, 64, 64, 128, 32, 1, t3, 9, F_INRELU);
    conv_mfma2_k<128><<<dim3(1024, 1), 256, 0, stream>>>(Ht, Lt, P2e1w2, nullptr,
        nullptr, H4, L4, H3, L3, 64, 64, 32, 128, 1, t1, 1, F_INRELU | F_RES);
    conv_mfma2_k<32><<<dim3(1024, 1), 256, 0, stream>>>(H4, L4, P2e2w1, nullptr,
        nullptr, Ht, Lt, nullptr, nullptr, 64, 64, 128, 32, 1, t3, 9, F_INRELU);
    conv_mfma2_k<128><<<dim3(1024, 1), 256, 0, stream>>>(Ht, Lt, P2e2w2, nullptr,
        outF, Fh, Fl, H4, L4, 64, 64, 32, 128, 1, t1, 1, F_INRELU | F_RES | F_OUTRELU);

    // ---- VQ ----
    vq_mfma_k<<<1024, 256, 0, stream>>>(Fh, Fl, Pe, EN, emb, outQ, Qb);

    // ---- decoder (bf16 MFMA; residual pairs fused) ----
    conv_mfma_k<128><<<dim3(1024, 1), 256, 0, stream>>>(Qb, Pdec, dec_b, Y0, Db, nullptr,
        128, 128, 64, 64, 1, 0, 0, t3, 9, 0);
    dres_k<<<1024, 256, 0, stream>>>(Db, Pd1w1, Pd1w2, Y0, Y1, Y1b, t3, 0);
    dres_k<<<1024, 256, 0, stream>>>(Y1b, Pd2w1, Pd2w2, Y1, nullptr, Y2b, t3, 1);
    for (int p = 0; p < 4; ++p)
        conv_mfma_k<64><<<dim3(1024, 1), 256, 0, stream>>>(Y2b, Pdt1[p], dt1_b, A1, nullptr, nullptr,
            128, 64, 128, 128, 2, p >> 1, p & 1, tdt[p], 4, F_OUTRELU);

    // ---- dt2 (fp16 MFMA, A-hi only + B hi/lo) ----
    dt2_mfma_k<<<16384, 256, 0, stream>>>(A1, Pdt2, dt2_b, outY);
}